// Round 12
// baseline (309.934 us; speedup 1.0000x reference)
//
#include <hip/hip_runtime.h>
#include <hip/hip_bf16.h>
#include <cstdint>

constexpr int Bb  = 8;
constexpr int Ls  = 1024;
constexpr int DM  = 512;
constexpr int NH  = 8;
constexpr int DHd = 64;
constexpr int MR  = Bb * Ls;   // 8192 rows
constexpr int ZH  = Bb * NH;   // 64 (b,h) pairs

typedef __attribute__((ext_vector_type(8))) short short8v;
typedef __attribute__((ext_vector_type(4))) short short4v;
typedef __attribute__((ext_vector_type(4))) float floatx4;

__device__ inline short f2bf(float x) {
  __hip_bfloat16 h = __float2bfloat16(x);
  return *reinterpret_cast<short*>(&h);
}
__device__ inline float bf2f(short s) {
  return __uint_as_float(((uint32_t)(uint16_t)s) << 16);
}

#define GLOAD_LDS16(g, l)                                                        \
  __builtin_amdgcn_global_load_lds(                                              \
      (const __attribute__((address_space(1))) void*)(g),                        \
      (__attribute__((address_space(3))) void*)(l), 16, 0, 0)

// ========= bf16 MFMA GEMM, 3-buffer 2-deep pipeline (counted vmcnt) =========
// MODE: 1 bf16 out |
// 10 L1 triple (N=1536: Q->Qzb bf16 compact, K->Kzb bf16 compact, V->merged f32)
//    aux2 = V f32 merged; aux3 = QKzb base (Qzb, then Kzb at +ZH*Ls*64)
// 12 L2 triple (N=1536: Q(x1)->Qb bf16 x0.125, K(mem)->Kb swizzled, V(mem)->Vt
//    transposed, vectorized); aux3 = second A matrix (mem) used for bn>=512
// 20 split-K raw f32 partial (no bias; partial z -> Cout/aux1)
template<int MODE, int RELU>
__global__ __launch_bounds__(256) void k_gemm_mfma(
    const __hip_bfloat16* __restrict__ A, const __hip_bfloat16* __restrict__ Wt,
    const float* __restrict__ bias, const float* __restrict__ bias1,
    const float* __restrict__ bias2,
    void* __restrict__ Cout, void* __restrict__ aux1, void* __restrict__ aux2,
    void* __restrict__ aux3,
    int M, int N, int K)
{
  __shared__ __hip_bfloat16 As[3][128 * 32];
  __shared__ __hip_bfloat16 Bs[3][128 * 32];
  const int tid = threadIdx.x;
  const int w = tid >> 6, lane = tid & 63;
  const int wr = w >> 1, wc = w & 1;
  const int bm = blockIdx.x * 128, bn = blockIdx.y * 128;
  const int lrow = lane >> 2;
  const int lcol = (lane & 3) * 8;
  const int fr = lane & 15;
  const int fco = (lane >> 4) * 8;

  const __hip_bfloat16* Asrc = A;
  if (MODE == 12 && bn >= 512) Asrc = (const __hip_bfloat16*)aux3;

  const int ksl = K / gridDim.z;
  const int kb0 = blockIdx.z * ksl;
  const int nst = ksl / 32;

  const int chunk0 = w * 2, chunk1 = w * 2 + 1;
  const size_t aoff0 = (size_t)(bm + chunk0 * 16 + lrow) * K + lcol;
  const size_t aoff1 = (size_t)(bm + chunk1 * 16 + lrow) * K + lcol;
  const size_t boff0 = (size_t)(bn + chunk0 * 16 + lrow) * K + lcol;
  const size_t boff1 = (size_t)(bn + chunk1 * 16 + lrow) * K + lcol;

#define STAGE(tt, bf)                                                     \
  {                                                                       \
    const int k0s = kb0 + (tt) * 32;                                      \
    GLOAD_LDS16(Asrc + aoff0 + k0s, &As[bf][chunk0 * 512]);               \
    GLOAD_LDS16(Asrc + aoff1 + k0s, &As[bf][chunk1 * 512]);               \
    GLOAD_LDS16(Wt + boff0 + k0s, &Bs[bf][chunk0 * 512]);                 \
    GLOAD_LDS16(Wt + boff1 + k0s, &Bs[bf][chunk1 * 512]);                 \
  }

  // prologue: stage t=0 (+ t=1 if present); wait until t=0 landed
  STAGE(0, 0);
  if (nst > 1) {
    STAGE(1, 1);
    asm volatile("s_waitcnt vmcnt(4)" ::: "memory");
  } else {
    asm volatile("s_waitcnt vmcnt(0)" ::: "memory");
  }
  __builtin_amdgcn_s_barrier();

  floatx4 acc[4][4] = {};
  int cb = 0, ib = 2;                      // compute buffer, issue buffer
  for (int t = 0; t < nst; ++t) {
    if (t + 2 < nst) STAGE(t + 2, ib);
    const short* Ash = (const short*)As[cb];
    const short* Bsh = (const short*)Bs[cb];
    short8v a[4], b[4];
#pragma unroll
    for (int mi = 0; mi < 4; ++mi)
      a[mi] = *(const short8v*)(Ash + (wr * 64 + mi * 16 + fr) * 32 + fco);
#pragma unroll
    for (int ni = 0; ni < 4; ++ni)
      b[ni] = *(const short8v*)(Bsh + (wc * 64 + ni * 16 + fr) * 32 + fco);
    __builtin_amdgcn_s_setprio(1);
#pragma unroll
    for (int mi = 0; mi < 4; ++mi)
#pragma unroll
      for (int ni = 0; ni < 4; ++ni)
        acc[mi][ni] = __builtin_amdgcn_mfma_f32_16x16x32_bf16(
            a[mi], b[ni], acc[mi][ni], 0, 0, 0);
    __builtin_amdgcn_s_setprio(0);
    if (t + 1 < nst) {
      if (t + 2 < nst)
        asm volatile("s_waitcnt vmcnt(4)" ::: "memory");   // t+1 landed, t+2 in flight
      else
        asm volatile("s_waitcnt vmcnt(0)" ::: "memory");
      __builtin_amdgcn_s_barrier();
    }
    cb = (cb == 2) ? 0 : cb + 1;
    ib = (ib == 2) ? 0 : ib + 1;
  }
#undef STAGE
#pragma unroll
  for (int ni = 0; ni < 4; ++ni) {
    const int cn = bn + wc * 64 + ni * 16 + fr;
    float bv = 0.f;
    if (MODE == 10 || MODE == 12) {
      const float* bp = (cn < 512) ? bias : (cn < 1024 ? bias1 : bias2);
      bv = bp[cn & 511];
    } else if (MODE != 20) {
      bv = bias[cn];
    }
#pragma unroll
    for (int mi = 0; mi < 4; ++mi) {
      const int rm0 = bm + wr * 64 + mi * 16 + (lane >> 4) * 4;
      float vv[4];
#pragma unroll
      for (int j = 0; j < 4; ++j) {
        float v = acc[mi][ni][j] + bv;
        if (RELU) v = fmaxf(v, 0.f);
        vv[j] = v;
      }
      if (MODE == 1) {
#pragma unroll
        for (int j = 0; j < 4; ++j)
          ((__hip_bfloat16*)Cout)[(size_t)(rm0 + j) * N + cn] = __float2bfloat16(vv[j]);
      } else if (MODE == 10) {
        const int sel = cn >> 9, c = cn & 511;
        if (sel == 2) {
#pragma unroll
          for (int j = 0; j < 4; ++j)
            ((float*)aux2)[(size_t)(rm0 + j) * 512 + c] = vv[j];
        } else {
          const int hh = c >> 6, dd = c & 63;
          const int bb = rm0 >> 10, l0 = rm0 & 1023;
          __hip_bfloat16* bb16 = (__hip_bfloat16*)aux3 +
                                 (sel ? (size_t)ZH * Ls * 64 : 0);
#pragma unroll
          for (int j = 0; j < 4; ++j)
            bb16[(((size_t)(bb * 8 + hh)) * 1024 + l0 + j) * 64 + dd] =
                __float2bfloat16(vv[j]);
        }
      } else if (MODE == 12) {
        const int sel = cn >> 9, c = cn & 511;
        if (sel == 0) {
#pragma unroll
          for (int j = 0; j < 4; ++j)
            ((__hip_bfloat16*)Cout)[(size_t)(rm0 + j) * 512 + c] =
                __float2bfloat16(vv[j] * 0.125f);
        } else if (sel == 1) {
#pragma unroll
          for (int j = 0; j < 4; ++j) {
            const int rm = rm0 + j;
            const int cj = (c & ~63) | ((c & 63) ^ ((rm & 7) << 3));
            ((__hip_bfloat16*)aux1)[(size_t)rm * 512 + cj] = __float2bfloat16(vv[j]);
          }
        } else {
          const int hh = c >> 6, dd = c & 63;
          const int bb = rm0 >> 10, l0 = rm0 & 1023;
          short4v pk;
#pragma unroll
          for (int j = 0; j < 4; ++j) pk[j] = f2bf(vv[j]);
          *(short4v*)((__hip_bfloat16*)aux2 +
                      (size_t)((bb * 8 + hh) * 64 + dd) * 1024 +
                      ((l0 ^ ((dd & 7) << 3)))) = pk;
        }
      } else if (MODE == 20) {
        float* pz = (float*)(blockIdx.z == 0 ? Cout : aux1);
#pragma unroll
        for (int j = 0; j < 4; ++j)
          pz[(size_t)(rm0 + j) * N + cn] = vv[j];
      }
    }
  }
}

// ===== fused flash cross-attention v2: 512 thr, dbuf K/V, defer-max, setprio =====
__global__ __launch_bounds__(512) void k_flash2(
    const __hip_bfloat16* __restrict__ Qb,
    const __hip_bfloat16* __restrict__ Kb,
    const __hip_bfloat16* __restrict__ Vt,
    __hip_bfloat16* __restrict__ O)
{
  __shared__ __hip_bfloat16 Ks[2][64 * 64];
  __shared__ __hip_bfloat16 Vs[2][64 * 64];
  __shared__ __hip_bfloat16 Ps[8 * 16 * 72];
  const int tid = threadIdx.x, w = tid >> 6, lane = tid & 63;
  const int g = lane >> 4, r = lane & 15;
  const int z = blockIdx.y, b = z >> 3, h = z & 7;
  const int q0 = blockIdx.x * 128 + w * 16;
  __hip_bfloat16* Pw = Ps + w * 16 * 72;

  const int srow = w * 8 + (lane >> 3);
  const int sseg = lane & 7;

  const short8v qf0 = *(const short8v*)(Qb + (size_t)(b * Ls + q0 + r) * DM + h * DHd + g * 8);
  const short8v qf1 = *(const short8v*)(Qb + (size_t)(b * Ls + q0 + r) * DM + h * DHd + 32 + g * 8);

  floatx4 oacc[4] = {};
  float m_run = -1e30f, l_run = 0.f;

  GLOAD_LDS16(Kb + (size_t)(b * Ls + srow) * DM + h * DHd + sseg * 8, &Ks[0][w * 512]);
  GLOAD_LDS16(Vt + ((size_t)z * DHd + srow) * Ls + sseg * 8, &Vs[0][w * 512]);
  asm volatile("s_waitcnt vmcnt(0)" ::: "memory");
  __builtin_amdgcn_s_barrier();

  int cur = 0;
  for (int t = 0; t < 16; ++t) {
    if (t + 1 < 16) {
      GLOAD_LDS16(Kb + (size_t)(b * Ls + (t + 1) * 64 + srow) * DM + h * DHd + sseg * 8,
                  &Ks[cur ^ 1][w * 512]);
      GLOAD_LDS16(Vt + ((size_t)z * DHd + srow) * Ls + (t + 1) * 64 + sseg * 8,
                  &Vs[cur ^ 1][w * 512]);
    }
    const __hip_bfloat16* Kc = Ks[cur];
    const __hip_bfloat16* Vc = Vs[cur];
    float sv[4][4];
    float tmax = -1e30f;
    __builtin_amdgcn_s_setprio(1);
#pragma unroll
    for (int kt = 0; kt < 4; ++kt) {
      const int key = kt * 16 + r, sw = key & 7;
      short8v a0 = *(const short8v*)(Kc + key * 64 + ((g ^ sw) * 8));
      short8v a1 = *(const short8v*)(Kc + key * 64 + (((4 + g) ^ sw) * 8));
      floatx4 c = {};
      c = __builtin_amdgcn_mfma_f32_16x16x32_bf16(a0, qf0, c, 0, 0, 0);
      c = __builtin_amdgcn_mfma_f32_16x16x32_bf16(a1, qf1, c, 0, 0, 0);
#pragma unroll
      for (int j = 0; j < 4; ++j) {
        float x = c[j];
        sv[kt][j] = x;
        tmax = fmaxf(tmax, x);
      }
    }
    __builtin_amdgcn_s_setprio(0);
    tmax = fmaxf(tmax, __shfl_xor(tmax, 16));
    tmax = fmaxf(tmax, __shfl_xor(tmax, 32));
    float m_new;
    if (__all(tmax <= m_run + 8.0f)) {
      m_new = m_run;
    } else {
      m_new = fmaxf(m_run, tmax);
      const float fac = __expf(m_run - m_new);
      float fj[4];
#pragma unroll
      for (int j = 0; j < 4; ++j) fj[j] = __shfl(fac, (lane & 48) | (g * 4 + j));
#pragma unroll
      for (int ct = 0; ct < 4; ++ct)
#pragma unroll
        for (int j = 0; j < 4; ++j) oacc[ct][j] *= fj[j];
      l_run *= fac;
    }
    float psum = 0.f;
#pragma unroll
    for (int kt = 0; kt < 4; ++kt) {
      short4v pk;
#pragma unroll
      for (int j = 0; j < 4; ++j) {
        float p = __expf(sv[kt][j] - m_new);
        psum += p;
        pk[j] = f2bf(p);
      }
      *(short4v*)(Pw + r * 72 + kt * 16 + g * 4) = pk;
    }
    psum += __shfl_xor(psum, 16);
    psum += __shfl_xor(psum, 32);
    l_run += psum;
    m_run = m_new;
    const short8v pa0 = *(const short8v*)(Pw + r * 72 + g * 8);
    const short8v pa1 = *(const short8v*)(Pw + r * 72 + 32 + g * 8);
    __builtin_amdgcn_s_setprio(1);
#pragma unroll
    for (int ct = 0; ct < 4; ++ct) {
      const int d = ct * 16 + r, sw = d & 7;
      short8v v0 = *(const short8v*)(Vc + d * 64 + ((g ^ sw) * 8));
      short8v v1 = *(const short8v*)(Vc + d * 64 + (((4 + g) ^ sw) * 8));
      oacc[ct] = __builtin_amdgcn_mfma_f32_16x16x32_bf16(pa0, v0, oacc[ct], 0, 0, 0);
      oacc[ct] = __builtin_amdgcn_mfma_f32_16x16x32_bf16(pa1, v1, oacc[ct], 0, 0, 0);
    }
    __builtin_amdgcn_s_setprio(0);
    asm volatile("s_waitcnt vmcnt(0)" ::: "memory");
    __builtin_amdgcn_s_barrier();
    cur ^= 1;
  }
  float li[4];
#pragma unroll
  for (int j = 0; j < 4; ++j)
    li[j] = 1.0f / __shfl(l_run, (lane & 48) | (g * 4 + j));
#pragma unroll
  for (int ct = 0; ct < 4; ++ct)
#pragma unroll
    for (int j = 0; j < 4; ++j)
      O[(size_t)(b * Ls + q0 + g * 4 + j) * DM + h * DHd + ct * 16 + r] =
          __float2bfloat16(oacc[ct][j] * li[j]);
}

// ---------------- ALL converts (2 activations + 10 weights) in one dispatch ----------------
struct CvtArgs { const float* s[12]; __hip_bfloat16* d[12]; };
__global__ __launch_bounds__(256) void k_cvt_all(CvtArgs a)
{
  const int bid = blockIdx.x, tid = threadIdx.x;
  if (bid < 8192) {
    const size_t half = (size_t)MR * DM / 4;
    size_t i = (size_t)bid * 256 + tid;
    const float* in = a.s[10]; __hip_bfloat16* out = a.d[10];
    if (i >= half) { i -= half; in = a.s[11]; out = a.d[11]; }
    float4 v = *reinterpret_cast<const float4*>(in + i * 4);
    short4v o;
    o.x = f2bf(v.x); o.y = f2bf(v.y); o.z = f2bf(v.z); o.w = f2bf(v.w);
    *reinterpret_cast<short4v*>(out + i * 4) = o;
    return;
  }
  __shared__ float t[32][33];
  const int wb = bid - 8192;
  int widx, K, N, kblk, nblk;
  if (wb < 2048) {
    widx = wb >> 8; const int w2 = wb & 255;
    K = 512; N = 512; kblk = w2 & 15; nblk = w2 >> 4;
  } else if (wb < 3072) {
    widx = 8; const int w2 = wb - 2048;
    K = 512; N = 2048; kblk = w2 & 15; nblk = w2 >> 4;
  } else {
    widx = 9; const int w2 = wb - 3072;
    K = 2048; N = 512; kblk = w2 & 63; nblk = w2 >> 6;
  }
  const float* W = a.s[widx];
  __hip_bfloat16* Wt = a.d[widx];
  const int k0 = kblk * 32, n0 = nblk * 32;
  const int r = tid >> 3, c = (tid & 7) * 4;
  float4 v = *reinterpret_cast<const float4*>(W + (size_t)(k0 + r) * N + n0 + c);
  t[r][c + 0] = v.x; t[r][c + 1] = v.y; t[r][c + 2] = v.z; t[r][c + 3] = v.w;
  __syncthreads();
  short4v o;
  o.x = f2bf(t[c + 0][r]); o.y = f2bf(t[c + 1][r]);
  o.z = f2bf(t[c + 2][r]); o.w = f2bf(t[c + 3][r]);
  *reinterpret_cast<short4v*>(Wt + (size_t)(n0 + r) * K + k0 + c) = o;
}

// ====== fused prob attention chunk (bf16 Q/K in, f32 compute) ======
__global__ __launch_bounds__(256) void k_probflash(
    const __hip_bfloat16* __restrict__ Qzb, const __hip_bfloat16* __restrict__ Kzb,
    const float* __restrict__ Vm, const int* __restrict__ top,
    float* __restrict__ Op, float* __restrict__ Ml, float* __restrict__ Ll,
    float* __restrict__ mvp, int U)
{
  __shared__ float Qs[DHd][64 + 4];
  __shared__ float Ks[DHd][64 + 4];
  __shared__ float Vs[64][64];
  __shared__ float ps[4][64];
  const int bid = blockIdx.x;
  const int swz = (bid & 7) * ((16 * ZH) >> 3) + (bid >> 3);
  const int kc = swz & 15, z = swz >> 4, b = z >> 3, h = z & 7;
  const int tid = threadIdx.x;
  const int k0 = kc * 64;
#pragma unroll
  for (int i = 0; i < 4; ++i) {
    const int idx = tid + (i << 8);
    const int r = idx >> 4, c4 = (idx & 15) << 2;
    int u = r; if (u >= U) u = U - 1;
    const int qr = top[z * U + u];
    short4v q4 = *reinterpret_cast<const short4v*>(Qzb + ((size_t)z * Ls + qr) * 64 + c4);
    Qs[c4 + 0][r] = bf2f(q4.x); Qs[c4 + 1][r] = bf2f(q4.y);
    Qs[c4 + 2][r] = bf2f(q4.z); Qs[c4 + 3][r] = bf2f(q4.w);
    short4v k4 = *reinterpret_cast<const short4v*>(Kzb + ((size_t)z * Ls + k0 + r) * 64 + c4);
    Ks[c4 + 0][r] = bf2f(k4.x); Ks[c4 + 1][r] = bf2f(k4.y);
    Ks[c4 + 2][r] = bf2f(k4.z); Ks[c4 + 3][r] = bf2f(k4.w);
    *reinterpret_cast<float4*>(&Vs[r][c4]) =
        *reinterpret_cast<const float4*>(Vm + ((size_t)(b * Ls + k0 + r)) * DM + h * DHd + c4);
  }
  __syncthreads();
  const int mB = (tid >> 4) << 2, nB = (tid & 15) << 2;
  float acc[4][4] = {};
#pragma unroll
  for (int kk = 0; kk < DHd; ++kk) {
    float4 a4 = *reinterpret_cast<const float4*>(&Qs[kk][mB]);
    float4 b4 = *reinterpret_cast<const float4*>(&Ks[kk][nB]);
    const float av[4] = {a4.x, a4.y, a4.z, a4.w};
#pragma unroll
    for (int i = 0; i < 4; ++i) {
      acc[i][0] += av[i] * b4.x; acc[i][1] += av[i] * b4.y;
      acc[i][2] += av[i] * b4.z; acc[i][3] += av[i] * b4.w;
    }
  }
  __syncthreads();
  float (*Ss)[68] = (float (*)[68])Qs;
#pragma unroll
  for (int i = 0; i < 4; ++i) {
    float4 o;
    o.x = acc[i][0] * 0.125f; o.y = acc[i][1] * 0.125f;
    o.z = acc[i][2] * 0.125f; o.w = acc[i][3] * 0.125f;
    *reinterpret_cast<float4*>(&Ss[mB + i][nB]) = o;
  }
  __syncthreads();
  {
    const int row = tid >> 2, q = tid & 3;
    float mx = -1e30f;
#pragma unroll
    for (int j = 0; j < 16; ++j) mx = fmaxf(mx, Ss[row][q * 16 + j]);
    mx = fmaxf(mx, __shfl_xor(mx, 1));
    mx = fmaxf(mx, __shfl_xor(mx, 2));
    float se = 0.f;
#pragma unroll
    for (int j = 0; j < 16; ++j) {
      float p = __expf(Ss[row][q * 16 + j] - mx);
      Ss[row][q * 16 + j] = p;
      se += p;
    }
    se += __shfl_xor(se, 1);
    se += __shfl_xor(se, 2);
    if (q == 0) {
      Ml[((size_t)kc * ZH + z) * 64 + row] = mx;
      Ll[((size_t)kc * ZH + z) * 64 + row] = se;
    }
  }
  __syncthreads();
  const int d = tid & 63, w = tid >> 6;
  {
    float s = 0.f;
#pragma unroll
    for (int i = 0; i < 16; ++i) s += Vs[w * 16 + i][d];
    ps[w][d] = s;
  }
  float acc2[16] = {};
  for (int k = 0; k < 64; ++k) {
    const float vk = Vs[k][d];
#pragma unroll
    for (int i = 0; i < 16; ++i)
      acc2[i] += Ss[w * 16 + i][k] * vk;
  }
  float* outb = Op + ((size_t)kc * ZH + z) * 4096;
#pragma unroll
  for (int i = 0; i < 16; ++i)
    outb[(w * 16 + i) * 64 + d] = acc2[i];
  __syncthreads();
  if (w == 0)
    mvp[((size_t)z * 16 + kc) * 64 + d] = ps[0][d] + ps[1][d] + ps[2][d] + ps[3][d];
}

// ------ per-z: meanV fill of whole slice + flash-combine scatter of top-U ------
__global__ __launch_bounds__(256) void k_prob_comb2(
    const float* __restrict__ Op, const float* __restrict__ Ml,
    const float* __restrict__ Ll, const int* __restrict__ top,
    const float* __restrict__ mvp, __hip_bfloat16* __restrict__ ctx, int U)
{
  __shared__ float wsh[16][64];
  __shared__ float Lsh[64];
  __shared__ short4v mvb[16];
  const int z = blockIdx.x, b = z >> 3, h = z & 7;
  const int tid = threadIdx.x;
  if (tid < 64) {
    float M = -1e30f;
#pragma unroll
    for (int c = 0; c < 16; ++c)
      M = fmaxf(M, Ml[((size_t)c * ZH + z) * 64 + tid]);
    float L = 0.f;
#pragma unroll
    for (int c = 0; c < 16; ++c) {
      float wv = __expf(Ml[((size_t)c * ZH + z) * 64 + tid] - M);
      wsh[c][tid] = wv;
      L += wv * Ll[((size_t)c * ZH + z) * 64 + tid];
    }
    Lsh[tid] = L;
    float s = 0.f;
#pragma unroll
    for (int c = 0; c < 16; ++c) s += mvp[((size_t)z * 16 + c) * 64 + tid];
    const short mb = f2bf(s * (1.0f / Ls));
    ((short*)mvb)[tid] = mb;
  }
  __syncthreads();
  __hip_bfloat16* base = ctx + (size_t)(b * Ls) * DM + h * DHd;
  for (int i = tid; i < 1024 * 16; i += 256) {
    const int row = i >> 4, c4 = i & 15;
    *reinterpret_cast<short4v*>(base + (size_t)row * DM + c4 * 4) = mvb[c4];
  }
  __syncthreads();
  for (int e = tid; e < U * 64; e += 256) {
    const int u = e >> 6, d = e & 63;
    float s = 0.f;
#pragma unroll
    for (int c = 0; c < 16; ++c)
      s += wsh[c][u] * Op[((size_t)c * ZH + z) * 4096 + u * 64 + d];
    const int row = top[z * U + u];
    ctx[((size_t)(b * Ls + row)) * DM + h * DHd + d] =
        __float2bfloat16(s / Lsh[u]);
  }
}

// ---- ProbSparse sampled scores, bf16 compact gather, 8 lanes/query ----
template<int UU>
__global__ __launch_bounds__(256) void k_mscore4(
    const __hip_bfloat16* __restrict__ Qzb, const __hip_bfloat16* __restrict__ Kzb,
    const int* __restrict__ smp, float* __restrict__ Ms)
{
  const int bid = blockIdx.x;
  const int swz = (bid & 7) * 256 + (bid >> 3);
  const int gw = swz * 4 + (threadIdx.x >> 6);
  const int lane = threadIdx.x & 63;
  const int li = lane >> 3, dp = (lane & 7) * 8;
  const int l = (gw & 127) * 8 + li;
  const int z = gw >> 7;
  const short8v q8 = *(const short8v*)(Qzb + ((size_t)z * Ls + l) * 64 + dp);
  float qf[8];
#pragma unroll
  for (int j = 0; j < 8; ++j) qf[j] = bf2f(q8[j]);
  int kidx[UU];
#pragma unroll
  for (int u = 0; u < UU; ++u) kidx[u] = smp[l * UU + u];
  const __hip_bfloat16* kzb = Kzb + (size_t)z * Ls * 64 + dp;
  float mx = -1e30f, sm = 0.f;
#pragma unroll
  for (int u = 0; u < UU; ++u) {
    const short8v k8 = *(const short8v*)(kzb + (size_t)kidx[u] * 64);
    float d = qf[0] * bf2f(k8[0]) + qf[1] * bf2f(k8[1])
            + qf[2] * bf2f(k8[2]) + qf[3] * bf2f(k8[3])
            + qf[4] * bf2f(k8[4]) + qf[5] * bf2f(k8[5])
            + qf[6] * bf2f(k8[6]) + qf[7] * bf2f(k8[7]);
    d += __shfl_xor(d, 1);
    d += __shfl_xor(d, 2);
    d += __shfl_xor(d, 4);
    mx = fmaxf(mx, d);
    sm += d;
  }
  if ((lane & 7) == 0) Ms[z * Ls + l] = mx - sm * (1.0f / Ls);
}

// runtime-U fallback
__global__ __launch_bounds__(256) void k_mscore4g(
    const __hip_bfloat16* __restrict__ Qzb, const __hip_bfloat16* __restrict__ Kzb,
    const int* __restrict__ smp, float* __restrict__ Ms, int U)
{
  const int bid = blockIdx.x;
  const int swz = (bid & 7) * 256 + (bid >> 3);
  const int gw = swz * 4 + (threadIdx.x >> 6);
  const int lane = threadIdx.x & 63;
  const int li = lane >> 3, dp = (lane & 7) * 8;
  const int l = (gw & 127) * 8 + li;
  const int z = gw >> 7;
  const short8v q8 = *(const short8v*)(Qzb + ((size_t)z * Ls + l) * 64 + dp);
  float qf[8];
#pragma unroll
  for (int j = 0; j < 8; ++j) qf[j] = bf2f(q8[j]);
  const __hip_bfloat16* kzb = Kzb + (size_t)z * Ls * 64 + dp;
  float mx = -1e30f, sm = 0.f;
  for (int u = 0; u < U; ++u) {
    const short8v k8 = *(const short8v*)(kzb + (size_t)smp[l * U + u] * 64);
    float d = qf[0] * bf2f(k8[0]) + qf[1] * bf2f(k8[1])
            + qf[2] * bf2f(k8[2]) + qf[3] * bf2f(k8[3])
            + qf[4] * bf2f(k8[4]) + qf[5] * bf2f(k8[5])
            + qf[6] * bf2f(k8[6]) + qf[7] * bf2f(k8[7]);
    d += __shfl_xor(d, 1);
    d += __shfl_xor(d, 2);
    d += __shfl_xor(d, 4);
    mx = fmaxf(mx, d);
    sm += d;
  }
  if ((lane & 7) == 0) Ms[z * Ls + l] = mx - sm * (1.0f / Ls);
}

// ---------------- wave-parallel top-U ----------------
__global__ __launch_bounds__(64) void k_topk_w(
    const float* __restrict__ Ms, int* __restrict__ top, int U)
{
  const int z = blockIdx.x, lane = threadIdx.x;
  float v[16];
#pragma unroll
  for (int j = 0; j < 16; ++j) v[j] = Ms[z * Ls + j * 64 + lane];
  for (int it = 0; it < U; ++it) {
    float bv = -1e30f; int bi = 0x7fffffff;
#pragma unroll
    for (int j = 0; j < 16; ++j) {
      const int idx = j * 64 + lane;
      if (v[j] > bv) { bv = v[j]; bi = idx; }
    }
#pragma unroll
    for (int off = 1; off < 64; off <<= 1) {
      const float ov = __shfl_xor(bv, off);
      const int   oi = __shfl_xor(bi, off);
      if (ov > bv || (ov == bv && oi < bi)) { bv = ov; bi = oi; }
    }
    if (lane == 0) top[z * U + it] = bi;
    if ((bi & 63) == lane) v[bi >> 6] = -1e30f;
  }
}

// ------- LayerNorm over sum of NP partials (+bias) (+residual) -------
template<int NP>
__global__ __launch_bounds__(256) void k_ln2(
    const float* __restrict__ x0, const float* __restrict__ x1,
    const float* __restrict__ x2, const float* __restrict__ x3,
    const float* __restrict__ res, const float* __restrict__ bias,
    const float* __restrict__ g, const float* __restrict__ be,
    float* __restrict__ outf, __hip_bfloat16* __restrict__ outb)
{
  __shared__ float red[4];
  const int row = blockIdx.x, tid = threadIdx.x;
  const size_t base = (size_t)row * DM;
  float2 v = *reinterpret_cast<const float2*>(x0 + base + tid * 2);
  if (NP > 1) {
    float2 a = *reinterpret_cast<const float2*>(x1 + base + tid * 2);
    v.x += a.x; v.y += a.y;
  }
  if (NP > 2) {
    float2 a = *reinterpret_cast<const float2*>(x2 + base + tid * 2);
    v.x += a.x; v.y += a.y;
  }
  if (NP > 3) {
    float2 a = *reinterpret_cast<const float2*>(x3 + base + tid * 2);
    v.x += a.x; v.y += a.y;
  }
  if (bias) {
    float2 a = *reinterpret_cast<const float2*>(bias + tid * 2);
    v.x += a.x; v.y += a.y;
  }
  if (res) {
    float2 r2 = *reinterpret_cast<const float2*>(res + base + tid * 2);
    v.x += r2.x; v.y += r2.y;
  }
  float s = v.x + v.y;
#pragma unroll
  for (int off = 32; off; off >>= 1) s += __shfl_xor(s, off);
  if ((tid & 63) == 0) red[tid >> 6] = s;
  __syncthreads();
  s = red[0] + red[1] + red[2] + red[3];
  const float mean = s * (1.0f / DM);
  __syncthreads();
  float dx = v.x - mean, dy = v.y - mean;
  float q = dx * dx + dy * dy;
#pragma unroll
  for (int off = 32; off; off >>= 1) q += __shfl_xor(q, off);
  if ((tid & 63) == 0) red[tid >> 6] = q;
  __syncthreads();
  q = red[0] + red[1] + red[2] + red[3];
  const float inv = rsqrtf(q * (1.0f / DM) + 1e-5f);
  float2 gg = *reinterpret_cast<const float2*>(g + tid * 2);
  float2 bb = *reinterpret_cast<const float2*>(be + tid * 2);
  float ox = dx * inv * gg.x + bb.x;
  float oy = dy * inv * gg.y + bb.y;
  if (outf) {
    float2 o; o.x = ox; o.y = oy;
    *reinterpret_cast<float2*>(outf + base + tid * 2) = o;
  }
  if (outb) {
    short2 ob; ob.x = f2bf(ox); ob.y = f2bf(oy);
    *reinterpret_cast<short2*>(outb + base + tid * 2) = ob;
  }
}

extern "C" void kernel_launch(void* const* d_in, const int* in_sizes, int n_in,
                              void* d_out, int out_size, void* d_ws, size_t ws_size,
                              hipStream_t stream)
{
  const float* tgt = (const float*)d_in[0];
  const float* mem = (const float*)d_in[1];
  const int*   smp = (const int*)d_in[2];
  const float* wq1 = (const float*)d_in[3];  const float* bq1 = (const float*)d_in[4];
  const float* wk1 = (const float*)d_in[5];  const float* bk1 = (const float*)d_in[6];
  const float* wv1 = (const float*)d_in[7];  const float* bv1 = (const float*)d_in[8];
  const float* wo1 = (const float*)d_in[9];  const float* bo1 = (const float*)d_in[10];
  const float* wq2 = (const float*)d_in[11]; const float* bq2 = (const float*)d_in[12];
  const float* wk2 = (const float*)d_in[13]; const float* bk2 = (const float*)d_in[14];
  const float* wv2 = (const float*)d_in[15]; const float* bv2 = (const float*)d_in[16];
  const float* wo2 = (const float*)d_in[17]; const float* bo2 = (const float*)d_in[18];
  const float* c1w = (const float*)d_in[19]; const float* c1b = (const float*)d_in[20];
  const float* c2w = (const float*)d_in[21]; const float* c2b = (const float*)d_in[22];
  const float* g1  = (const float*)d_in[23]; const float* be1 = (const float*)d_in[24];
  const float* g2  = (const float*)d_in[25]; const float* be2 = (const float*)d_in[26];
  const float* g3  = (const float*)d_in[27]; const float* be3 = (const float*)d_in[28];
  float* outp = (float*)d_out;

  const int U   = in_sizes[2] / Ls;            // 35

  char* ws = (char*)d_ws;
  const size_t SZ = (size_t)MR * DM * sizeof(float);       // 16.78 MB
  float* W0   = (float*)(ws);
  float* W1   = (float*)(ws + SZ);
  float* W2   = (float*)(ws + 2 * SZ);
  float* Sbuf = (float*)(ws + 3 * SZ);                     // FFN hidden / QKzb region
  float* Op   = Sbuf + (size_t)ZH * 64 * Ls;               // prob PV partials
  __hip_bfloat16* QKzb = (__hip_bfloat16*)Sbuf;            // Qzb, then Kzb
  __hip_bfloat16* Qzb = QKzb;
  __hip_bfloat16* Kzb = QKzb + (size_t)ZH * Ls * 64;
  __hip_bfloat16* Tb  = (__hip_bfloat16*)(ws + 5 * SZ);
  __hip_bfloat16* Mb  = (__hip_bfloat16*)(ws + 5 * SZ + SZ / 2);
  __hip_bfloat16* Xb  = (__hip_bfloat16*)(ws + 6 * SZ);
  __hip_bfloat16* Vtb = (__hip_bfloat16*)(ws + 6 * SZ + SZ / 2);
  __hip_bfloat16* Wt3 = Vtb;                 // [wq1b;wk1b;wv1b] (dead before Vtb written)
  char* tail = ws + 7 * SZ;
  __hip_bfloat16* wo1b = (__hip_bfloat16*)tail; tail += DM * DM * 2;
  __hip_bfloat16* wq2b = (__hip_bfloat16*)tail; tail += DM * DM * 2;
  __hip_bfloat16* wk2b = (__hip_bfloat16*)tail; tail += DM * DM * 2;
  __hip_bfloat16* wv2b = (__hip_bfloat16*)tail; tail += DM * DM * 2;
  __hip_bfloat16* wo2b = (__hip_bfloat16*)tail; tail += DM * DM * 2;
  __hip_bfloat16* c1wb = (__hip_bfloat16*)tail; tail += DM * 4 * DM * 2;
  __hip_bfloat16* c2wb = (__hip_bfloat16*)tail; tail += DM * 4 * DM * 2;
  float* Ms  = (float*)tail; tail += (size_t)ZH * Ls * 4;
  int*   top = (int*)tail;   tail += (size_t)ZH * 64 * 4;
  float* mvp = (float*)tail; tail += (size_t)ZH * 16 * DHd * 4;
  float* Ml  = (float*)tail; tail += (size_t)16 * ZH * 64 * 4;
  float* Ll  = (float*)tail; tail += (size_t)16 * ZH * 64 * 4;
  __hip_bfloat16* Kb = Tb;
  __hip_bfloat16* Qb = (__hip_bfloat16*)d_out;  // parked until final LN
  __hip_bfloat16* hb = (__hip_bfloat16*)Sbuf;

  // ---- ALL converts, one dispatch ----
  CvtArgs ca;
  ca.s[0] = wq1; ca.d[0] = Wt3;
  ca.s[1] = wk1; ca.d[1] = Wt3 + DM * DM;
  ca.s[2] = wv1; ca.d[2] = Wt3 + 2 * DM * DM;
  ca.s[3] = wo1; ca.d[3] = wo1b;
  ca.s[4] = wq2; ca.d[4] = wq2b;
  ca.s[5] = wk2; ca.d[5] = wk2b;
  ca.s[6] = wv2; ca.d[6] = wv2b;
  ca.s[7] = wo2; ca.d[7] = wo2b;
  ca.s[8] = c1w; ca.d[8] = c1wb;
  ca.s[9] = c2w; ca.d[9] = c2wb;
  ca.s[10] = tgt; ca.d[10] = Tb;
  ca.s[11] = mem; ca.d[11] = Mb;
  k_cvt_all<<<dim3(12288), 256, 0, stream>>>(ca);

  // ---- layer-1 projections: ONE batched GEMM (Q->Qzb, K->Kzb, V->W2 f32) ----
  k_gemm_mfma<10, 0><<<dim3(MR / 128, 12), 256, 0, stream>>>(
      Tb, Wt3, bq1, bk1, bv1, nullptr, nullptr, W2, QKzb, MR, 1536, DM);

  // ---- ProbSparse ----
  if (U == 35)
    k_mscore4<35><<<dim3(2048), 256, 0, stream>>>(Qzb, Kzb, smp, Ms);
  else
    k_mscore4g<<<dim3(2048), 256, 0, stream>>>(Qzb, Kzb, smp, Ms, U);
  k_topk_w<<<dim3(ZH), 64, 0, stream>>>(Ms, top, U);
  k_probflash<<<dim3(16 * ZH), 256, 0, stream>>>(Qzb, Kzb, W2, top, Op, Ml, Ll, mvp, U);
  k_prob_comb2<<<dim3(ZH), 256, 0, stream>>>(Op, Ml, Ll, top, mvp, Xb, U);

  // ---- out-proj 1 (split-K=2) + residual LN (fused reduce) ----
  k_gemm_mfma<20, 0><<<dim3(MR / 128, DM / 128, 2), 256, 0, stream>>>(
      Xb, wo1b, nullptr, nullptr, nullptr, W0, W1, nullptr, nullptr, MR, DM, DM);
  k_ln2<2><<<dim3(MR), 256, 0, stream>>>(W0, W1, nullptr, nullptr,
                                         tgt, bo1, g1, be1, nullptr, Xb);

  // ---- layer-2 projections: ONE triple (Q from Xb; K,V from Mb via aux3) ----
  k_gemm_mfma<12, 0><<<dim3(MR / 128, 12), 256, 0, stream>>>(
      Xb, wq2b, bq2, bk2, bv2, Qb, Kb, Vtb, (void*)Mb, MR, 1536, DM);

  // ---- fused flash cross attention -> Xb (bf16) ----
  k_flash2<<<dim3(Ls / 128, ZH), 512, 0, stream>>>(Qb, Kb, Vtb, Xb);

  // ---- out-proj 2 (split-K=2) + LN (fused) ----
  k_gemm_mfma<20, 0><<<dim3(MR / 128, DM / 128, 2), 256, 0, stream>>>(
      Xb, wo2b, nullptr, nullptr, nullptr, W0, W2, nullptr, nullptr, MR, DM, DM);
  k_ln2<2><<<dim3(MR), 256, 0, stream>>>(W0, W2, nullptr, nullptr,
                                         nullptr, bo2, g2, be2, W1, Xb);

  // ---- FFN ----
  k_gemm_mfma<1, 1><<<dim3(MR / 128, 4 * DM / 128), 256, 0, stream>>>(
      Xb, c1wb, c1b, nullptr, nullptr, hb, nullptr, nullptr, nullptr, MR, 4 * DM, DM);
  k_gemm_mfma<20, 0><<<dim3(MR / 128, DM / 128, 2), 256, 0, stream>>>(
      hb, c2wb, nullptr, nullptr, nullptr, W0, W2, nullptr, nullptr, MR, DM, 2 * DM * 2);
  k_ln2<2><<<dim3(MR), 256, 0, stream>>>(W0, W2, nullptr, nullptr,
                                         W1, c2b, g3, be3, outp, nullptr);
}

// Round 13
// 306.396 us; speedup vs baseline: 1.0115x; 1.0115x over previous
//
#include <hip/hip_runtime.h>
#include <hip/hip_bf16.h>
#include <cstdint>

constexpr int Bb  = 8;
constexpr int Ls  = 1024;
constexpr int DM  = 512;
constexpr int NH  = 8;
constexpr int DHd = 64;
constexpr int MR  = Bb * Ls;   // 8192 rows
constexpr int ZH  = Bb * NH;   // 64 (b,h) pairs

typedef __attribute__((ext_vector_type(8))) short short8v;
typedef __attribute__((ext_vector_type(4))) short short4v;
typedef __attribute__((ext_vector_type(4))) float floatx4;

__device__ inline short f2bf(float x) {
  __hip_bfloat16 h = __float2bfloat16(x);
  return *reinterpret_cast<short*>(&h);
}
__device__ inline float bf2f(short s) {
  return __uint_as_float(((uint32_t)(uint16_t)s) << 16);
}

#define GLOAD_LDS16(g, l)                                                        \
  __builtin_amdgcn_global_load_lds(                                              \
      (const __attribute__((address_space(1))) void*)(g),                        \
      (__attribute__((address_space(3))) void*)(l), 16, 0, 0)

// ================= bf16 MFMA GEMM, double-buffered prefetch =================
// MODE: 1 bf16 out |
// 10 L1 triple (N=1536: Q->Qzb bf16 compact, K->Kzb bf16 compact, V->merged f32)
//    aux2 = V f32 merged; aux3 = QKzb base (Qzb, then Kzb at +ZH*Ls*64)
// 12 L2 triple (N=1536: Q(x1)->Qb bf16 x0.125, K(mem)->Kb swizzled, V(mem)->Vt
//    transposed, vectorized); aux3 = second A matrix (mem) used for bn>=512
// 20 split-K raw f32 partial (no bias; partial z -> Cout/aux1)
template<int MODE, int RELU>
__global__ __launch_bounds__(256) void k_gemm_mfma(
    const __hip_bfloat16* __restrict__ A, const __hip_bfloat16* __restrict__ Wt,
    const float* __restrict__ bias, const float* __restrict__ bias1,
    const float* __restrict__ bias2,
    void* __restrict__ Cout, void* __restrict__ aux1, void* __restrict__ aux2,
    void* __restrict__ aux3,
    int M, int N, int K)
{
  __shared__ __hip_bfloat16 As[2][128 * 32];
  __shared__ __hip_bfloat16 Bs[2][128 * 32];
  const int tid = threadIdx.x;
  const int w = tid >> 6, lane = tid & 63;
  const int wr = w >> 1, wc = w & 1;
  const int bm = blockIdx.x * 128, bn = blockIdx.y * 128;
  const int lrow = lane >> 2;
  const int lcol = (lane & 3) * 8;
  const int fr = lane & 15;
  const int fco = (lane >> 4) * 8;

  const __hip_bfloat16* Asrc = A;
  if (MODE == 12 && bn >= 512) Asrc = (const __hip_bfloat16*)aux3;

  const int ksl = K / gridDim.z;
  const int kb0 = blockIdx.z * ksl;
  const int nst = ksl / 32;

  const int chunk0 = w * 2, chunk1 = w * 2 + 1;
  const size_t aoff0 = (size_t)(bm + chunk0 * 16 + lrow) * K + lcol;
  const size_t aoff1 = (size_t)(bm + chunk1 * 16 + lrow) * K + lcol;
  const size_t boff0 = (size_t)(bn + chunk0 * 16 + lrow) * K + lcol;
  const size_t boff1 = (size_t)(bn + chunk1 * 16 + lrow) * K + lcol;

  {
    const int k0 = kb0;
    GLOAD_LDS16(Asrc + aoff0 + k0, &As[0][chunk0 * 512]);
    GLOAD_LDS16(Asrc + aoff1 + k0, &As[0][chunk1 * 512]);
    GLOAD_LDS16(Wt + boff0 + k0, &Bs[0][chunk0 * 512]);
    GLOAD_LDS16(Wt + boff1 + k0, &Bs[0][chunk1 * 512]);
  }
  asm volatile("s_waitcnt vmcnt(0)" ::: "memory");
  __builtin_amdgcn_s_barrier();

  floatx4 acc[4][4] = {};
  int cur = 0;
  for (int t = 0; t < nst; ++t) {
    if (t + 1 < nst) {
      const int k0 = kb0 + (t + 1) * 32;
      GLOAD_LDS16(Asrc + aoff0 + k0, &As[cur ^ 1][chunk0 * 512]);
      GLOAD_LDS16(Asrc + aoff1 + k0, &As[cur ^ 1][chunk1 * 512]);
      GLOAD_LDS16(Wt + boff0 + k0, &Bs[cur ^ 1][chunk0 * 512]);
      GLOAD_LDS16(Wt + boff1 + k0, &Bs[cur ^ 1][chunk1 * 512]);
    }
    const short* Ash = (const short*)As[cur];
    const short* Bsh = (const short*)Bs[cur];
    short8v a[4], b[4];
#pragma unroll
    for (int mi = 0; mi < 4; ++mi)
      a[mi] = *(const short8v*)(Ash + (wr * 64 + mi * 16 + fr) * 32 + fco);
#pragma unroll
    for (int ni = 0; ni < 4; ++ni)
      b[ni] = *(const short8v*)(Bsh + (wc * 64 + ni * 16 + fr) * 32 + fco);
#pragma unroll
    for (int mi = 0; mi < 4; ++mi)
#pragma unroll
      for (int ni = 0; ni < 4; ++ni)
        acc[mi][ni] = __builtin_amdgcn_mfma_f32_16x16x32_bf16(
            a[mi], b[ni], acc[mi][ni], 0, 0, 0);
    asm volatile("s_waitcnt vmcnt(0)" ::: "memory");
    __builtin_amdgcn_s_barrier();
    cur ^= 1;
  }
#pragma unroll
  for (int ni = 0; ni < 4; ++ni) {
    const int cn = bn + wc * 64 + ni * 16 + fr;
    float bv = 0.f;
    if (MODE == 10 || MODE == 12) {
      const float* bp = (cn < 512) ? bias : (cn < 1024 ? bias1 : bias2);
      bv = bp[cn & 511];
    } else if (MODE != 20) {
      bv = bias[cn];
    }
#pragma unroll
    for (int mi = 0; mi < 4; ++mi) {
      const int rm0 = bm + wr * 64 + mi * 16 + (lane >> 4) * 4;
      float vv[4];
#pragma unroll
      for (int j = 0; j < 4; ++j) {
        float v = acc[mi][ni][j] + bv;
        if (RELU) v = fmaxf(v, 0.f);
        vv[j] = v;
      }
      if (MODE == 1) {
#pragma unroll
        for (int j = 0; j < 4; ++j)
          ((__hip_bfloat16*)Cout)[(size_t)(rm0 + j) * N + cn] = __float2bfloat16(vv[j]);
      } else if (MODE == 10) {
        const int sel = cn >> 9, c = cn & 511;
        if (sel == 2) {
#pragma unroll
          for (int j = 0; j < 4; ++j)
            ((float*)aux2)[(size_t)(rm0 + j) * 512 + c] = vv[j];
        } else {
          const int hh = c >> 6, dd = c & 63;
          const int bb = rm0 >> 10, l0 = rm0 & 1023;
          __hip_bfloat16* bb16 = (__hip_bfloat16*)aux3 +
                                 (sel ? (size_t)ZH * Ls * 64 : 0);
#pragma unroll
          for (int j = 0; j < 4; ++j)
            bb16[(((size_t)(bb * 8 + hh)) * 1024 + l0 + j) * 64 + dd] =
                __float2bfloat16(vv[j]);
        }
      } else if (MODE == 12) {
        const int sel = cn >> 9, c = cn & 511;
        if (sel == 0) {
#pragma unroll
          for (int j = 0; j < 4; ++j)
            ((__hip_bfloat16*)Cout)[(size_t)(rm0 + j) * 512 + c] =
                __float2bfloat16(vv[j] * 0.125f);
        } else if (sel == 1) {
#pragma unroll
          for (int j = 0; j < 4; ++j) {
            const int rm = rm0 + j;
            const int cj = (c & ~63) | ((c & 63) ^ ((rm & 7) << 3));
            ((__hip_bfloat16*)aux1)[(size_t)rm * 512 + cj] = __float2bfloat16(vv[j]);
          }
        } else {
          const int hh = c >> 6, dd = c & 63;
          const int bb = rm0 >> 10, l0 = rm0 & 1023;
          short4v pk;
#pragma unroll
          for (int j = 0; j < 4; ++j) pk[j] = f2bf(vv[j]);
          *(short4v*)((__hip_bfloat16*)aux2 +
                      (size_t)((bb * 8 + hh) * 64 + dd) * 1024 +
                      ((l0 ^ ((dd & 7) << 3)))) = pk;
        }
      } else if (MODE == 20) {
        float* pz = (float*)(blockIdx.z == 0 ? Cout : aux1);
#pragma unroll
        for (int j = 0; j < 4; ++j)
          pz[(size_t)(rm0 + j) * N + cn] = vv[j];
      }
    }
  }
}

// ===== fused flash cross-attention v2: 512 thr, dbuf K/V, defer-max, setprio =====
__global__ __launch_bounds__(512) void k_flash2(
    const __hip_bfloat16* __restrict__ Qb,
    const __hip_bfloat16* __restrict__ Kb,
    const __hip_bfloat16* __restrict__ Vt,
    __hip_bfloat16* __restrict__ O)
{
  __shared__ __hip_bfloat16 Ks[2][64 * 64];
  __shared__ __hip_bfloat16 Vs[2][64 * 64];
  __shared__ __hip_bfloat16 Ps[8 * 16 * 72];
  const int tid = threadIdx.x, w = tid >> 6, lane = tid & 63;
  const int g = lane >> 4, r = lane & 15;
  const int z = blockIdx.y, b = z >> 3, h = z & 7;
  const int q0 = blockIdx.x * 128 + w * 16;
  __hip_bfloat16* Pw = Ps + w * 16 * 72;

  const int srow = w * 8 + (lane >> 3);
  const int sseg = lane & 7;

  const short8v qf0 = *(const short8v*)(Qb + (size_t)(b * Ls + q0 + r) * DM + h * DHd + g * 8);
  const short8v qf1 = *(const short8v*)(Qb + (size_t)(b * Ls + q0 + r) * DM + h * DHd + 32 + g * 8);

  floatx4 oacc[4] = {};
  float m_run = -1e30f, l_run = 0.f;

  GLOAD_LDS16(Kb + (size_t)(b * Ls + srow) * DM + h * DHd + sseg * 8, &Ks[0][w * 512]);
  GLOAD_LDS16(Vt + ((size_t)z * DHd + srow) * Ls + sseg * 8, &Vs[0][w * 512]);
  asm volatile("s_waitcnt vmcnt(0)" ::: "memory");
  __builtin_amdgcn_s_barrier();

  int cur = 0;
  for (int t = 0; t < 16; ++t) {
    if (t + 1 < 16) {
      GLOAD_LDS16(Kb + (size_t)(b * Ls + (t + 1) * 64 + srow) * DM + h * DHd + sseg * 8,
                  &Ks[cur ^ 1][w * 512]);
      GLOAD_LDS16(Vt + ((size_t)z * DHd + srow) * Ls + (t + 1) * 64 + sseg * 8,
                  &Vs[cur ^ 1][w * 512]);
    }
    const __hip_bfloat16* Kc = Ks[cur];
    const __hip_bfloat16* Vc = Vs[cur];
    float sv[4][4];
    float tmax = -1e30f;
    __builtin_amdgcn_s_setprio(1);
#pragma unroll
    for (int kt = 0; kt < 4; ++kt) {
      const int key = kt * 16 + r, sw = key & 7;
      short8v a0 = *(const short8v*)(Kc + key * 64 + ((g ^ sw) * 8));
      short8v a1 = *(const short8v*)(Kc + key * 64 + (((4 + g) ^ sw) * 8));
      floatx4 c = {};
      c = __builtin_amdgcn_mfma_f32_16x16x32_bf16(a0, qf0, c, 0, 0, 0);
      c = __builtin_amdgcn_mfma_f32_16x16x32_bf16(a1, qf1, c, 0, 0, 0);
#pragma unroll
      for (int j = 0; j < 4; ++j) {
        float x = c[j];
        sv[kt][j] = x;
        tmax = fmaxf(tmax, x);
      }
    }
    __builtin_amdgcn_s_setprio(0);
    tmax = fmaxf(tmax, __shfl_xor(tmax, 16));
    tmax = fmaxf(tmax, __shfl_xor(tmax, 32));
    float m_new;
    if (__all(tmax <= m_run + 8.0f)) {
      m_new = m_run;
    } else {
      m_new = fmaxf(m_run, tmax);
      const float fac = __expf(m_run - m_new);
      float fj[4];
#pragma unroll
      for (int j = 0; j < 4; ++j) fj[j] = __shfl(fac, (lane & 48) | (g * 4 + j));
#pragma unroll
      for (int ct = 0; ct < 4; ++ct)
#pragma unroll
        for (int j = 0; j < 4; ++j) oacc[ct][j] *= fj[j];
      l_run *= fac;
    }
    float psum = 0.f;
#pragma unroll
    for (int kt = 0; kt < 4; ++kt) {
      short4v pk;
#pragma unroll
      for (int j = 0; j < 4; ++j) {
        float p = __expf(sv[kt][j] - m_new);
        psum += p;
        pk[j] = f2bf(p);
      }
      *(short4v*)(Pw + r * 72 + kt * 16 + g * 4) = pk;
    }
    psum += __shfl_xor(psum, 16);
    psum += __shfl_xor(psum, 32);
    l_run += psum;
    m_run = m_new;
    const short8v pa0 = *(const short8v*)(Pw + r * 72 + g * 8);
    const short8v pa1 = *(const short8v*)(Pw + r * 72 + 32 + g * 8);
    __builtin_amdgcn_s_setprio(1);
#pragma unroll
    for (int ct = 0; ct < 4; ++ct) {
      const int d = ct * 16 + r, sw = d & 7;
      short8v v0 = *(const short8v*)(Vc + d * 64 + ((g ^ sw) * 8));
      short8v v1 = *(const short8v*)(Vc + d * 64 + (((4 + g) ^ sw) * 8));
      oacc[ct] = __builtin_amdgcn_mfma_f32_16x16x32_bf16(pa0, v0, oacc[ct], 0, 0, 0);
      oacc[ct] = __builtin_amdgcn_mfma_f32_16x16x32_bf16(pa1, v1, oacc[ct], 0, 0, 0);
    }
    __builtin_amdgcn_s_setprio(0);
    asm volatile("s_waitcnt vmcnt(0)" ::: "memory");
    __builtin_amdgcn_s_barrier();
    cur ^= 1;
  }
  float li[4];
#pragma unroll
  for (int j = 0; j < 4; ++j)
    li[j] = 1.0f / __shfl(l_run, (lane & 48) | (g * 4 + j));
#pragma unroll
  for (int ct = 0; ct < 4; ++ct)
#pragma unroll
    for (int j = 0; j < 4; ++j)
      O[(size_t)(b * Ls + q0 + g * 4 + j) * DM + h * DHd + ct * 16 + r] =
          __float2bfloat16(oacc[ct][j] * li[j]);
}

// ---------------- ALL converts (2 activations + 10 weights) in one dispatch ----------------
struct CvtArgs { const float* s[12]; __hip_bfloat16* d[12]; };
__global__ __launch_bounds__(256) void k_cvt_all(CvtArgs a)
{
  const int bid = blockIdx.x, tid = threadIdx.x;
  if (bid < 8192) {
    const size_t half = (size_t)MR * DM / 4;
    size_t i = (size_t)bid * 256 + tid;
    const float* in = a.s[10]; __hip_bfloat16* out = a.d[10];
    if (i >= half) { i -= half; in = a.s[11]; out = a.d[11]; }
    float4 v = *reinterpret_cast<const float4*>(in + i * 4);
    short4v o;
    o.x = f2bf(v.x); o.y = f2bf(v.y); o.z = f2bf(v.z); o.w = f2bf(v.w);
    *reinterpret_cast<short4v*>(out + i * 4) = o;
    return;
  }
  __shared__ float t[32][33];
  const int wb = bid - 8192;
  int widx, K, N, kblk, nblk;
  if (wb < 2048) {
    widx = wb >> 8; const int w2 = wb & 255;
    K = 512; N = 512; kblk = w2 & 15; nblk = w2 >> 4;
  } else if (wb < 3072) {
    widx = 8; const int w2 = wb - 2048;
    K = 512; N = 2048; kblk = w2 & 15; nblk = w2 >> 4;
  } else {
    widx = 9; const int w2 = wb - 3072;
    K = 2048; N = 512; kblk = w2 & 63; nblk = w2 >> 6;
  }
  const float* W = a.s[widx];
  __hip_bfloat16* Wt = a.d[widx];
  const int k0 = kblk * 32, n0 = nblk * 32;
  const int r = tid >> 3, c = (tid & 7) * 4;
  float4 v = *reinterpret_cast<const float4*>(W + (size_t)(k0 + r) * N + n0 + c);
  t[r][c + 0] = v.x; t[r][c + 1] = v.y; t[r][c + 2] = v.z; t[r][c + 3] = v.w;
  __syncthreads();
  short4v o;
  o.x = f2bf(t[c + 0][r]); o.y = f2bf(t[c + 1][r]);
  o.z = f2bf(t[c + 2][r]); o.w = f2bf(t[c + 3][r]);
  *reinterpret_cast<short4v*>(Wt + (size_t)(n0 + r) * K + k0 + c) = o;
}

// ====== fused prob attention chunk (bf16 Q/K in, f32 compute) ======
__global__ __launch_bounds__(256) void k_probflash(
    const __hip_bfloat16* __restrict__ Qzb, const __hip_bfloat16* __restrict__ Kzb,
    const float* __restrict__ Vm, const int* __restrict__ top,
    float* __restrict__ Op, float* __restrict__ Ml, float* __restrict__ Ll,
    float* __restrict__ mvp, int U)
{
  __shared__ float Qs[DHd][64 + 4];
  __shared__ float Ks[DHd][64 + 4];
  __shared__ float Vs[64][64];
  __shared__ float ps[4][64];
  const int bid = blockIdx.x;
  const int swz = (bid & 7) * ((16 * ZH) >> 3) + (bid >> 3);
  const int kc = swz & 15, z = swz >> 4, b = z >> 3, h = z & 7;
  const int tid = threadIdx.x;
  const int k0 = kc * 64;
#pragma unroll
  for (int i = 0; i < 4; ++i) {
    const int idx = tid + (i << 8);
    const int r = idx >> 4, c4 = (idx & 15) << 2;
    int u = r; if (u >= U) u = U - 1;
    const int qr = top[z * U + u];
    short4v q4 = *reinterpret_cast<const short4v*>(Qzb + ((size_t)z * Ls + qr) * 64 + c4);
    Qs[c4 + 0][r] = bf2f(q4.x); Qs[c4 + 1][r] = bf2f(q4.y);
    Qs[c4 + 2][r] = bf2f(q4.z); Qs[c4 + 3][r] = bf2f(q4.w);
    short4v k4 = *reinterpret_cast<const short4v*>(Kzb + ((size_t)z * Ls + k0 + r) * 64 + c4);
    Ks[c4 + 0][r] = bf2f(k4.x); Ks[c4 + 1][r] = bf2f(k4.y);
    Ks[c4 + 2][r] = bf2f(k4.z); Ks[c4 + 3][r] = bf2f(k4.w);
    *reinterpret_cast<float4*>(&Vs[r][c4]) =
        *reinterpret_cast<const float4*>(Vm + ((size_t)(b * Ls + k0 + r)) * DM + h * DHd + c4);
  }
  __syncthreads();
  const int mB = (tid >> 4) << 2, nB = (tid & 15) << 2;
  float acc[4][4] = {};
#pragma unroll
  for (int kk = 0; kk < DHd; ++kk) {
    float4 a4 = *reinterpret_cast<const float4*>(&Qs[kk][mB]);
    float4 b4 = *reinterpret_cast<const float4*>(&Ks[kk][nB]);
    const float av[4] = {a4.x, a4.y, a4.z, a4.w};
#pragma unroll
    for (int i = 0; i < 4; ++i) {
      acc[i][0] += av[i] * b4.x; acc[i][1] += av[i] * b4.y;
      acc[i][2] += av[i] * b4.z; acc[i][3] += av[i] * b4.w;
    }
  }
  __syncthreads();
  float (*Ss)[68] = (float (*)[68])Qs;
#pragma unroll
  for (int i = 0; i < 4; ++i) {
    float4 o;
    o.x = acc[i][0] * 0.125f; o.y = acc[i][1] * 0.125f;
    o.z = acc[i][2] * 0.125f; o.w = acc[i][3] * 0.125f;
    *reinterpret_cast<float4*>(&Ss[mB + i][nB]) = o;
  }
  __syncthreads();
  {
    const int row = tid >> 2, q = tid & 3;
    float mx = -1e30f;
#pragma unroll
    for (int j = 0; j < 16; ++j) mx = fmaxf(mx, Ss[row][q * 16 + j]);
    mx = fmaxf(mx, __shfl_xor(mx, 1));
    mx = fmaxf(mx, __shfl_xor(mx, 2));
    float se = 0.f;
#pragma unroll
    for (int j = 0; j < 16; ++j) {
      float p = __expf(Ss[row][q * 16 + j] - mx);
      Ss[row][q * 16 + j] = p;
      se += p;
    }
    se += __shfl_xor(se, 1);
    se += __shfl_xor(se, 2);
    if (q == 0) {
      Ml[((size_t)kc * ZH + z) * 64 + row] = mx;
      Ll[((size_t)kc * ZH + z) * 64 + row] = se;
    }
  }
  __syncthreads();
  const int d = tid & 63, w = tid >> 6;
  {
    float s = 0.f;
#pragma unroll
    for (int i = 0; i < 16; ++i) s += Vs[w * 16 + i][d];
    ps[w][d] = s;
  }
  float acc2[16] = {};
  for (int k = 0; k < 64; ++k) {
    const float vk = Vs[k][d];
#pragma unroll
    for (int i = 0; i < 16; ++i)
      acc2[i] += Ss[w * 16 + i][k] * vk;
  }
  float* outb = Op + ((size_t)kc * ZH + z) * 4096;
#pragma unroll
  for (int i = 0; i < 16; ++i)
    outb[(w * 16 + i) * 64 + d] = acc2[i];
  __syncthreads();
  if (w == 0)
    mvp[((size_t)z * 16 + kc) * 64 + d] = ps[0][d] + ps[1][d] + ps[2][d] + ps[3][d];
}

// ------ per-z: meanV fill of whole slice + flash-combine scatter of top-U ------
__global__ __launch_bounds__(256) void k_prob_comb2(
    const float* __restrict__ Op, const float* __restrict__ Ml,
    const float* __restrict__ Ll, const int* __restrict__ top,
    const float* __restrict__ mvp, __hip_bfloat16* __restrict__ ctx, int U)
{
  __shared__ float wsh[16][64];
  __shared__ float Lsh[64];
  __shared__ short4v mvb[16];
  const int z = blockIdx.x, b = z >> 3, h = z & 7;
  const int tid = threadIdx.x;
  if (tid < 64) {
    float M = -1e30f;
#pragma unroll
    for (int c = 0; c < 16; ++c)
      M = fmaxf(M, Ml[((size_t)c * ZH + z) * 64 + tid]);
    float L = 0.f;
#pragma unroll
    for (int c = 0; c < 16; ++c) {
      float wv = __expf(Ml[((size_t)c * ZH + z) * 64 + tid] - M);
      wsh[c][tid] = wv;
      L += wv * Ll[((size_t)c * ZH + z) * 64 + tid];
    }
    Lsh[tid] = L;
    float s = 0.f;
#pragma unroll
    for (int c = 0; c < 16; ++c) s += mvp[((size_t)z * 16 + c) * 64 + tid];
    const short mb = f2bf(s * (1.0f / Ls));
    ((short*)mvb)[tid] = mb;
  }
  __syncthreads();
  __hip_bfloat16* base = ctx + (size_t)(b * Ls) * DM + h * DHd;
  for (int i = tid; i < 1024 * 16; i += 256) {
    const int row = i >> 4, c4 = i & 15;
    *reinterpret_cast<short4v*>(base + (size_t)row * DM + c4 * 4) = mvb[c4];
  }
  __syncthreads();
  for (int e = tid; e < U * 64; e += 256) {
    const int u = e >> 6, d = e & 63;
    float s = 0.f;
#pragma unroll
    for (int c = 0; c < 16; ++c)
      s += wsh[c][u] * Op[((size_t)c * ZH + z) * 4096 + u * 64 + d];
    const int row = top[z * U + u];
    ctx[((size_t)(b * Ls + row)) * DM + h * DHd + d] =
        __float2bfloat16(s / Lsh[u]);
  }
}

// ---- ProbSparse sampled scores, bf16 compact gather, 8 lanes/query ----
template<int UU>
__global__ __launch_bounds__(256) void k_mscore4(
    const __hip_bfloat16* __restrict__ Qzb, const __hip_bfloat16* __restrict__ Kzb,
    const int* __restrict__ smp, float* __restrict__ Ms)
{
  const int bid = blockIdx.x;
  const int swz = (bid & 7) * 256 + (bid >> 3);
  const int gw = swz * 4 + (threadIdx.x >> 6);
  const int lane = threadIdx.x & 63;
  const int li = lane >> 3, dp = (lane & 7) * 8;
  const int l = (gw & 127) * 8 + li;
  const int z = gw >> 7;
  const short8v q8 = *(const short8v*)(Qzb + ((size_t)z * Ls + l) * 64 + dp);
  float qf[8];
#pragma unroll
  for (int j = 0; j < 8; ++j) qf[j] = bf2f(q8[j]);
  int kidx[UU];
#pragma unroll
  for (int u = 0; u < UU; ++u) kidx[u] = smp[l * UU + u];
  const __hip_bfloat16* kzb = Kzb + (size_t)z * Ls * 64 + dp;
  float mx = -1e30f, sm = 0.f;
#pragma unroll
  for (int u = 0; u < UU; ++u) {
    const short8v k8 = *(const short8v*)(kzb + (size_t)kidx[u] * 64);
    float d = qf[0] * bf2f(k8[0]) + qf[1] * bf2f(k8[1])
            + qf[2] * bf2f(k8[2]) + qf[3] * bf2f(k8[3])
            + qf[4] * bf2f(k8[4]) + qf[5] * bf2f(k8[5])
            + qf[6] * bf2f(k8[6]) + qf[7] * bf2f(k8[7]);
    d += __shfl_xor(d, 1);
    d += __shfl_xor(d, 2);
    d += __shfl_xor(d, 4);
    mx = fmaxf(mx, d);
    sm += d;
  }
  if ((lane & 7) == 0) Ms[z * Ls + l] = mx - sm * (1.0f / Ls);
}

// runtime-U fallback
__global__ __launch_bounds__(256) void k_mscore4g(
    const __hip_bfloat16* __restrict__ Qzb, const __hip_bfloat16* __restrict__ Kzb,
    const int* __restrict__ smp, float* __restrict__ Ms, int U)
{
  const int bid = blockIdx.x;
  const int swz = (bid & 7) * 256 + (bid >> 3);
  const int gw = swz * 4 + (threadIdx.x >> 6);
  const int lane = threadIdx.x & 63;
  const int li = lane >> 3, dp = (lane & 7) * 8;
  const int l = (gw & 127) * 8 + li;
  const int z = gw >> 7;
  const short8v q8 = *(const short8v*)(Qzb + ((size_t)z * Ls + l) * 64 + dp);
  float qf[8];
#pragma unroll
  for (int j = 0; j < 8; ++j) qf[j] = bf2f(q8[j]);
  const __hip_bfloat16* kzb = Kzb + (size_t)z * Ls * 64 + dp;
  float mx = -1e30f, sm = 0.f;
  for (int u = 0; u < U; ++u) {
    const short8v k8 = *(const short8v*)(kzb + (size_t)smp[l * U + u] * 64);
    float d = qf[0] * bf2f(k8[0]) + qf[1] * bf2f(k8[1])
            + qf[2] * bf2f(k8[2]) + qf[3] * bf2f(k8[3])
            + qf[4] * bf2f(k8[4]) + qf[5] * bf2f(k8[5])
            + qf[6] * bf2f(k8[6]) + qf[7] * bf2f(k8[7]);
    d += __shfl_xor(d, 1);
    d += __shfl_xor(d, 2);
    d += __shfl_xor(d, 4);
    mx = fmaxf(mx, d);
    sm += d;
  }
  if ((lane & 7) == 0) Ms[z * Ls + l] = mx - sm * (1.0f / Ls);
}

// ---------------- wave-parallel top-U ----------------
__global__ __launch_bounds__(64) void k_topk_w(
    const float* __restrict__ Ms, int* __restrict__ top, int U)
{
  const int z = blockIdx.x, lane = threadIdx.x;
  float v[16];
#pragma unroll
  for (int j = 0; j < 16; ++j) v[j] = Ms[z * Ls + j * 64 + lane];
  for (int it = 0; it < U; ++it) {
    float bv = -1e30f; int bi = 0x7fffffff;
#pragma unroll
    for (int j = 0; j < 16; ++j) {
      const int idx = j * 64 + lane;
      if (v[j] > bv) { bv = v[j]; bi = idx; }
    }
#pragma unroll
    for (int off = 1; off < 64; off <<= 1) {
      const float ov = __shfl_xor(bv, off);
      const int   oi = __shfl_xor(bi, off);
      if (ov > bv || (ov == bv && oi < bi)) { bv = ov; bi = oi; }
    }
    if (lane == 0) top[z * U + it] = bi;
    if ((bi & 63) == lane) v[bi >> 6] = -1e30f;
  }
}

// ------- LayerNorm over sum of NP partials (+bias) (+residual) -------
template<int NP>
__global__ __launch_bounds__(256) void k_ln2(
    const float* __restrict__ x0, const float* __restrict__ x1,
    const float* __restrict__ x2, const float* __restrict__ x3,
    const float* __restrict__ res, const float* __restrict__ bias,
    const float* __restrict__ g, const float* __restrict__ be,
    float* __restrict__ outf, __hip_bfloat16* __restrict__ outb)
{
  __shared__ float red[4];
  const int row = blockIdx.x, tid = threadIdx.x;
  const size_t base = (size_t)row * DM;
  float2 v = *reinterpret_cast<const float2*>(x0 + base + tid * 2);
  if (NP > 1) {
    float2 a = *reinterpret_cast<const float2*>(x1 + base + tid * 2);
    v.x += a.x; v.y += a.y;
  }
  if (NP > 2) {
    float2 a = *reinterpret_cast<const float2*>(x2 + base + tid * 2);
    v.x += a.x; v.y += a.y;
  }
  if (NP > 3) {
    float2 a = *reinterpret_cast<const float2*>(x3 + base + tid * 2);
    v.x += a.x; v.y += a.y;
  }
  if (bias) {
    float2 a = *reinterpret_cast<const float2*>(bias + tid * 2);
    v.x += a.x; v.y += a.y;
  }
  if (res) {
    float2 r2 = *reinterpret_cast<const float2*>(res + base + tid * 2);
    v.x += r2.x; v.y += r2.y;
  }
  float s = v.x + v.y;
#pragma unroll
  for (int off = 32; off; off >>= 1) s += __shfl_xor(s, off);
  if ((tid & 63) == 0) red[tid >> 6] = s;
  __syncthreads();
  s = red[0] + red[1] + red[2] + red[3];
  const float mean = s * (1.0f / DM);
  __syncthreads();
  float dx = v.x - mean, dy = v.y - mean;
  float q = dx * dx + dy * dy;
#pragma unroll
  for (int off = 32; off; off >>= 1) q += __shfl_xor(q, off);
  if ((tid & 63) == 0) red[tid >> 6] = q;
  __syncthreads();
  q = red[0] + red[1] + red[2] + red[3];
  const float inv = rsqrtf(q * (1.0f / DM) + 1e-5f);
  float2 gg = *reinterpret_cast<const float2*>(g + tid * 2);
  float2 bb = *reinterpret_cast<const float2*>(be + tid * 2);
  float ox = dx * inv * gg.x + bb.x;
  float oy = dy * inv * gg.y + bb.y;
  if (outf) {
    float2 o; o.x = ox; o.y = oy;
    *reinterpret_cast<float2*>(outf + base + tid * 2) = o;
  }
  if (outb) {
    short2 ob; ob.x = f2bf(ox); ob.y = f2bf(oy);
    *reinterpret_cast<short2*>(outb + base + tid * 2) = ob;
  }
}

extern "C" void kernel_launch(void* const* d_in, const int* in_sizes, int n_in,
                              void* d_out, int out_size, void* d_ws, size_t ws_size,
                              hipStream_t stream)
{
  const float* tgt = (const float*)d_in[0];
  const float* mem = (const float*)d_in[1];
  const int*   smp = (const int*)d_in[2];
  const float* wq1 = (const float*)d_in[3];  const float* bq1 = (const float*)d_in[4];
  const float* wk1 = (const float*)d_in[5];  const float* bk1 = (const float*)d_in[6];
  const float* wv1 = (const float*)d_in[7];  const float* bv1 = (const float*)d_in[8];
  const float* wo1 = (const float*)d_in[9];  const float* bo1 = (const float*)d_in[10];
  const float* wq2 = (const float*)d_in[11]; const float* bq2 = (const float*)d_in[12];
  const float* wk2 = (const float*)d_in[13]; const float* bk2 = (const float*)d_in[14];
  const float* wv2 = (const float*)d_in[15]; const float* bv2 = (const float*)d_in[16];
  const float* wo2 = (const float*)d_in[17]; const float* bo2 = (const float*)d_in[18];
  const float* c1w = (const float*)d_in[19]; const float* c1b = (const float*)d_in[20];
  const float* c2w = (const float*)d_in[21]; const float* c2b = (const float*)d_in[22];
  const float* g1  = (const float*)d_in[23]; const float* be1 = (const float*)d_in[24];
  const float* g2  = (const float*)d_in[25]; const float* be2 = (const float*)d_in[26];
  const float* g3  = (const float*)d_in[27]; const float* be3 = (const float*)d_in[28];
  float* outp = (float*)d_out;

  const int U   = in_sizes[2] / Ls;            // 35

  char* ws = (char*)d_ws;
  const size_t SZ = (size_t)MR * DM * sizeof(float);       // 16.78 MB
  float* W0   = (float*)(ws);
  float* W1   = (float*)(ws + SZ);
  float* W2   = (float*)(ws + 2 * SZ);
  float* Sbuf = (float*)(ws + 3 * SZ);                     // FFN hidden / QKzb region
  float* Op   = Sbuf + (size_t)ZH * 64 * Ls;               // prob PV partials
  __hip_bfloat16* QKzb = (__hip_bfloat16*)Sbuf;            // Qzb, then Kzb
  __hip_bfloat16* Qzb = QKzb;
  __hip_bfloat16* Kzb = QKzb + (size_t)ZH * Ls * 64;
  __hip_bfloat16* Tb  = (__hip_bfloat16*)(ws + 5 * SZ);
  __hip_bfloat16* Mb  = (__hip_bfloat16*)(ws + 5 * SZ + SZ / 2);
  __hip_bfloat16* Xb  = (__hip_bfloat16*)(ws + 6 * SZ);
  __hip_bfloat16* Vtb = (__hip_bfloat16*)(ws + 6 * SZ + SZ / 2);
  __hip_bfloat16* Wt3 = Vtb;                 // [wq1b;wk1b;wv1b] (dead before Vtb written)
  char* tail = ws + 7 * SZ;
  __hip_bfloat16* wo1b = (__hip_bfloat16*)tail; tail += DM * DM * 2;
  __hip_bfloat16* wq2b = (__hip_bfloat16*)tail; tail += DM * DM * 2;
  __hip_bfloat16* wk2b = (__hip_bfloat16*)tail; tail += DM * DM * 2;
  __hip_bfloat16* wv2b = (__hip_bfloat16*)tail; tail += DM * DM * 2;
  __hip_bfloat16* wo2b = (__hip_bfloat16*)tail; tail += DM * DM * 2;
  __hip_bfloat16* c1wb = (__hip_bfloat16*)tail; tail += DM * 4 * DM * 2;
  __hip_bfloat16* c2wb = (__hip_bfloat16*)tail; tail += DM * 4 * DM * 2;
  float* Ms  = (float*)tail; tail += (size_t)ZH * Ls * 4;
  int*   top = (int*)tail;   tail += (size_t)ZH * 64 * 4;
  float* mvp = (float*)tail; tail += (size_t)ZH * 16 * DHd * 4;
  float* Ml  = (float*)tail; tail += (size_t)16 * ZH * 64 * 4;
  float* Ll  = (float*)tail; tail += (size_t)16 * ZH * 64 * 4;
  __hip_bfloat16* Kb = Tb;
  __hip_bfloat16* Qb = (__hip_bfloat16*)d_out;  // parked until final LN
  __hip_bfloat16* hb = (__hip_bfloat16*)Sbuf;

  // ---- ALL converts, one dispatch ----
  CvtArgs ca;
  ca.s[0] = wq1; ca.d[0] = Wt3;
  ca.s[1] = wk1; ca.d[1] = Wt3 + DM * DM;
  ca.s[2] = wv1; ca.d[2] = Wt3 + 2 * DM * DM;
  ca.s[3] = wo1; ca.d[3] = wo1b;
  ca.s[4] = wq2; ca.d[4] = wq2b;
  ca.s[5] = wk2; ca.d[5] = wk2b;
  ca.s[6] = wv2; ca.d[6] = wv2b;
  ca.s[7] = wo2; ca.d[7] = wo2b;
  ca.s[8] = c1w; ca.d[8] = c1wb;
  ca.s[9] = c2w; ca.d[9] = c2wb;
  ca.s[10] = tgt; ca.d[10] = Tb;
  ca.s[11] = mem; ca.d[11] = Mb;
  k_cvt_all<<<dim3(12288), 256, 0, stream>>>(ca);

  // ---- layer-1 projections: ONE batched GEMM (Q->Qzb, K->Kzb, V->W2 f32) ----
  k_gemm_mfma<10, 0><<<dim3(MR / 128, 12), 256, 0, stream>>>(
      Tb, Wt3, bq1, bk1, bv1, nullptr, nullptr, W2, QKzb, MR, 1536, DM);

  // ---- ProbSparse ----
  if (U == 35)
    k_mscore4<35><<<dim3(2048), 256, 0, stream>>>(Qzb, Kzb, smp, Ms);
  else
    k_mscore4g<<<dim3(2048), 256, 0, stream>>>(Qzb, Kzb, smp, Ms, U);
  k_topk_w<<<dim3(ZH), 64, 0, stream>>>(Ms, top, U);
  k_probflash<<<dim3(16 * ZH), 256, 0, stream>>>(Qzb, Kzb, W2, top, Op, Ml, Ll, mvp, U);
  k_prob_comb2<<<dim3(ZH), 256, 0, stream>>>(Op, Ml, Ll, top, mvp, Xb, U);

  // ---- out-proj 1 (split-K=2) + residual LN (fused reduce) ----
  k_gemm_mfma<20, 0><<<dim3(MR / 128, DM / 128, 2), 256, 0, stream>>>(
      Xb, wo1b, nullptr, nullptr, nullptr, W0, W1, nullptr, nullptr, MR, DM, DM);
  k_ln2<2><<<dim3(MR), 256, 0, stream>>>(W0, W1, nullptr, nullptr,
                                         tgt, bo1, g1, be1, nullptr, Xb);

  // ---- layer-2 projections: ONE triple (Q from Xb; K,V from Mb via aux3) ----
  k_gemm_mfma<12, 0><<<dim3(MR / 128, 12), 256, 0, stream>>>(
      Xb, wq2b, bq2, bk2, bv2, Qb, Kb, Vtb, (void*)Mb, MR, 1536, DM);

  // ---- fused flash cross attention -> Xb (bf16) ----
  k_flash2<<<dim3(Ls / 128, ZH), 512, 0, stream>>>(Qb, Kb, Vtb, Xb);

  // ---- out-proj 2 (split-K=2) + LN (fused) ----
  k_gemm_mfma<20, 0><<<dim3(MR / 128, DM / 128, 2), 256, 0, stream>>>(
      Xb, wo2b, nullptr, nullptr, nullptr, W0, W2, nullptr, nullptr, MR, DM, DM);
  k_ln2<2><<<dim3(MR), 256, 0, stream>>>(W0, W2, nullptr, nullptr,
                                         nullptr, bo2, g2, be2, W1, Xb);

  // ---- FFN ----
  k_gemm_mfma<1, 1><<<dim3(MR / 128, 4 * DM / 128), 256, 0, stream>>>(
      Xb, c1wb, c1b, nullptr, nullptr, hb, nullptr, nullptr, nullptr, MR, 4 * DM, DM);
  k_gemm_mfma<20, 0><<<dim3(MR / 128, DM / 128, 2), 256, 0, stream>>>(
      hb, c2wb, nullptr, nullptr, nullptr, W0, W2, nullptr, nullptr, MR, DM, 2 * DM * 2);
  k_ln2<2><<<dim3(MR), 256, 0, stream>>>(W0, W2, nullptr, nullptr,
                                         W1, c2b, g3, be3, outp, nullptr);
}

// Round 14
// 304.464 us; speedup vs baseline: 1.0180x; 1.0063x over previous
//
#include <hip/hip_runtime.h>
#include <hip/hip_bf16.h>
#include <cstdint>

constexpr int Bb  = 8;
constexpr int Ls  = 1024;
constexpr int DM  = 512;
constexpr int NH  = 8;
constexpr int DHd = 64;
constexpr int MR  = Bb * Ls;   // 8192 rows
constexpr int ZH  = Bb * NH;   // 64 (b,h) pairs

typedef __attribute__((ext_vector_type(8))) short short8v;
typedef __attribute__((ext_vector_type(4))) short short4v;
typedef __attribute__((ext_vector_type(4))) float floatx4;

__device__ inline short f2bf(float x) {
  __hip_bfloat16 h = __float2bfloat16(x);
  return *reinterpret_cast<short*>(&h);
}
__device__ inline float bf2f(short s) {
  return __uint_as_float(((uint32_t)(uint16_t)s) << 16);
}

#define GLOAD_LDS16(g, l)                                                        \
  __builtin_amdgcn_global_load_lds(                                              \
      (const __attribute__((address_space(1))) void*)(g),                        \
      (__attribute__((address_space(3))) void*)(l), 16, 0, 0)

// ================= bf16 MFMA GEMM, double-buffered prefetch =================
// BMT: 128 (M-tile 128, 2 A-chunks/wave) or 64 (M-tile 64, 1 A-chunk/wave).
// MODE: 1 bf16 out |
// 10 L1 triple (N=1536: Q->Qzb bf16 compact, K->Kzb bf16 compact, V->merged f32)
//    aux2 = V f32 merged; aux3 = QKzb base (Qzb, then Kzb at +ZH*Ls*64)
// 12 L2 triple (N=1536: Q(x1)->Qb bf16 x0.125, K(mem)->Kb swizzled, V(mem)->Vt
//    transposed, vectorized); aux3 = second A matrix (mem) used for bn>=512
// 20 raw f32 out (no bias; gridDim.z==1 -> Cout, z==1 -> aux1)
template<int MODE, int RELU, int BMT>
__global__ __launch_bounds__(256) void k_gemm_mfma(
    const __hip_bfloat16* __restrict__ A, const __hip_bfloat16* __restrict__ Wt,
    const float* __restrict__ bias, const float* __restrict__ bias1,
    const float* __restrict__ bias2,
    void* __restrict__ Cout, void* __restrict__ aux1, void* __restrict__ aux2,
    void* __restrict__ aux3,
    int M, int N, int K)
{
  constexpr int MI  = (BMT == 128) ? 4 : 2;   // acc M-fragments per wave
  constexpr int WRS = (BMT == 128) ? 64 : 32; // wave M-extent
  __shared__ __hip_bfloat16 As[2][BMT * 32];
  __shared__ __hip_bfloat16 Bs[2][128 * 32];
  const int tid = threadIdx.x;
  const int w = tid >> 6, lane = tid & 63;
  const int wr = w >> 1, wc = w & 1;
  const int bm = blockIdx.x * BMT, bn = blockIdx.y * 128;
  const int lrow = lane >> 2;
  const int lcol = (lane & 3) * 8;
  const int fr = lane & 15;
  const int fco = (lane >> 4) * 8;

  const __hip_bfloat16* Asrc = A;
  if (MODE == 12 && bn >= 512) Asrc = (const __hip_bfloat16*)aux3;

  const int ksl = K / gridDim.z;
  const int kb0 = blockIdx.z * ksl;
  const int nst = ksl / 32;

  const int bchunk0 = w * 2, bchunk1 = w * 2 + 1;
  const size_t boff0 = (size_t)(bn + bchunk0 * 16 + lrow) * K + lcol;
  const size_t boff1 = (size_t)(bn + bchunk1 * 16 + lrow) * K + lcol;
  // A staging: BMT=128 -> chunks w*2, w*2+1 ; BMT=64 -> chunk w
  const int achunk0 = (BMT == 128) ? w * 2 : w;
  const size_t aoff0 = (size_t)(bm + achunk0 * 16 + lrow) * K + lcol;
  const size_t aoff1 = (BMT == 128)
      ? (size_t)(bm + (w * 2 + 1) * 16 + lrow) * K + lcol : 0;

#define STAGE_T(k0s, bf)                                                   \
  {                                                                        \
    GLOAD_LDS16(Asrc + aoff0 + (k0s), &As[bf][achunk0 * 512]);             \
    if (BMT == 128)                                                        \
      GLOAD_LDS16(Asrc + aoff1 + (k0s), &As[bf][(w * 2 + 1) * 512]);       \
    GLOAD_LDS16(Wt + boff0 + (k0s), &Bs[bf][bchunk0 * 512]);               \
    GLOAD_LDS16(Wt + boff1 + (k0s), &Bs[bf][bchunk1 * 512]);               \
  }

  STAGE_T(kb0, 0);
  asm volatile("s_waitcnt vmcnt(0)" ::: "memory");
  __builtin_amdgcn_s_barrier();

  floatx4 acc[MI][4] = {};
  int cur = 0;
  for (int t = 0; t < nst; ++t) {
    if (t + 1 < nst) STAGE_T(kb0 + (t + 1) * 32, cur ^ 1);
    const short* Ash = (const short*)As[cur];
    const short* Bsh = (const short*)Bs[cur];
    short8v a[MI], b[4];
#pragma unroll
    for (int mi = 0; mi < MI; ++mi)
      a[mi] = *(const short8v*)(Ash + (wr * WRS + mi * 16 + fr) * 32 + fco);
#pragma unroll
    for (int ni = 0; ni < 4; ++ni)
      b[ni] = *(const short8v*)(Bsh + (wc * 64 + ni * 16 + fr) * 32 + fco);
#pragma unroll
    for (int mi = 0; mi < MI; ++mi)
#pragma unroll
      for (int ni = 0; ni < 4; ++ni)
        acc[mi][ni] = __builtin_amdgcn_mfma_f32_16x16x32_bf16(
            a[mi], b[ni], acc[mi][ni], 0, 0, 0);
    asm volatile("s_waitcnt vmcnt(0)" ::: "memory");
    __builtin_amdgcn_s_barrier();
    cur ^= 1;
  }
#undef STAGE_T
#pragma unroll
  for (int ni = 0; ni < 4; ++ni) {
    const int cn = bn + wc * 64 + ni * 16 + fr;
    float bv = 0.f;
    if (MODE == 10 || MODE == 12) {
      const float* bp = (cn < 512) ? bias : (cn < 1024 ? bias1 : bias2);
      bv = bp[cn & 511];
    } else if (MODE != 20) {
      bv = bias[cn];
    }
#pragma unroll
    for (int mi = 0; mi < MI; ++mi) {
      const int rm0 = bm + wr * WRS + mi * 16 + (lane >> 4) * 4;
      float vv[4];
#pragma unroll
      for (int j = 0; j < 4; ++j) {
        float v = acc[mi][ni][j] + bv;
        if (RELU) v = fmaxf(v, 0.f);
        vv[j] = v;
      }
      if (MODE == 1) {
#pragma unroll
        for (int j = 0; j < 4; ++j)
          ((__hip_bfloat16*)Cout)[(size_t)(rm0 + j) * N + cn] = __float2bfloat16(vv[j]);
      } else if (MODE == 10) {
        const int sel = cn >> 9, c = cn & 511;
        if (sel == 2) {
#pragma unroll
          for (int j = 0; j < 4; ++j)
            ((float*)aux2)[(size_t)(rm0 + j) * 512 + c] = vv[j];
        } else {
          const int hh = c >> 6, dd = c & 63;
          const int bb = rm0 >> 10, l0 = rm0 & 1023;
          __hip_bfloat16* bb16 = (__hip_bfloat16*)aux3 +
                                 (sel ? (size_t)ZH * Ls * 64 : 0);
#pragma unroll
          for (int j = 0; j < 4; ++j)
            bb16[(((size_t)(bb * 8 + hh)) * 1024 + l0 + j) * 64 + dd] =
                __float2bfloat16(vv[j]);
        }
      } else if (MODE == 12) {
        const int sel = cn >> 9, c = cn & 511;
        if (sel == 0) {
#pragma unroll
          for (int j = 0; j < 4; ++j)
            ((__hip_bfloat16*)Cout)[(size_t)(rm0 + j) * 512 + c] =
                __float2bfloat16(vv[j] * 0.125f);
        } else if (sel == 1) {
#pragma unroll
          for (int j = 0; j < 4; ++j) {
            const int rm = rm0 + j;
            const int cj = (c & ~63) | ((c & 63) ^ ((rm & 7) << 3));
            ((__hip_bfloat16*)aux1)[(size_t)rm * 512 + cj] = __float2bfloat16(vv[j]);
          }
        } else {
          const int hh = c >> 6, dd = c & 63;
          const int bb = rm0 >> 10, l0 = rm0 & 1023;
          short4v pk;
#pragma unroll
          for (int j = 0; j < 4; ++j) pk[j] = f2bf(vv[j]);
          *(short4v*)((__hip_bfloat16*)aux2 +
                      (size_t)((bb * 8 + hh) * 64 + dd) * 1024 +
                      ((l0 ^ ((dd & 7) << 3)))) = pk;
        }
      } else if (MODE == 20) {
        float* pz = (float*)(blockIdx.z == 0 ? Cout : aux1);
#pragma unroll
        for (int j = 0; j < 4; ++j)
          pz[(size_t)(rm0 + j) * N + cn] = vv[j];
      }
    }
  }
}

// ===== fused flash cross-attention v2: 512 thr, dbuf K/V, defer-max, setprio =====
__global__ __launch_bounds__(512) void k_flash2(
    const __hip_bfloat16* __restrict__ Qb,
    const __hip_bfloat16* __restrict__ Kb,
    const __hip_bfloat16* __restrict__ Vt,
    __hip_bfloat16* __restrict__ O)
{
  __shared__ __hip_bfloat16 Ks[2][64 * 64];
  __shared__ __hip_bfloat16 Vs[2][64 * 64];
  __shared__ __hip_bfloat16 Ps[8 * 16 * 72];
  const int tid = threadIdx.x, w = tid >> 6, lane = tid & 63;
  const int g = lane >> 4, r = lane & 15;
  const int z = blockIdx.y, b = z >> 3, h = z & 7;
  const int q0 = blockIdx.x * 128 + w * 16;
  __hip_bfloat16* Pw = Ps + w * 16 * 72;

  const int srow = w * 8 + (lane >> 3);
  const int sseg = lane & 7;

  const short8v qf0 = *(const short8v*)(Qb + (size_t)(b * Ls + q0 + r) * DM + h * DHd + g * 8);
  const short8v qf1 = *(const short8v*)(Qb + (size_t)(b * Ls + q0 + r) * DM + h * DHd + 32 + g * 8);

  floatx4 oacc[4] = {};
  float m_run = -1e30f, l_run = 0.f;

  GLOAD_LDS16(Kb + (size_t)(b * Ls + srow) * DM + h * DHd + sseg * 8, &Ks[0][w * 512]);
  GLOAD_LDS16(Vt + ((size_t)z * DHd + srow) * Ls + sseg * 8, &Vs[0][w * 512]);
  asm volatile("s_waitcnt vmcnt(0)" ::: "memory");
  __builtin_amdgcn_s_barrier();

  int cur = 0;
  for (int t = 0; t < 16; ++t) {
    if (t + 1 < 16) {
      GLOAD_LDS16(Kb + (size_t)(b * Ls + (t + 1) * 64 + srow) * DM + h * DHd + sseg * 8,
                  &Ks[cur ^ 1][w * 512]);
      GLOAD_LDS16(Vt + ((size_t)z * DHd + srow) * Ls + (t + 1) * 64 + sseg * 8,
                  &Vs[cur ^ 1][w * 512]);
    }
    const __hip_bfloat16* Kc = Ks[cur];
    const __hip_bfloat16* Vc = Vs[cur];
    float sv[4][4];
    float tmax = -1e30f;
    __builtin_amdgcn_s_setprio(1);
#pragma unroll
    for (int kt = 0; kt < 4; ++kt) {
      const int key = kt * 16 + r, sw = key & 7;
      short8v a0 = *(const short8v*)(Kc + key * 64 + ((g ^ sw) * 8));
      short8v a1 = *(const short8v*)(Kc + key * 64 + (((4 + g) ^ sw) * 8));
      floatx4 c = {};
      c = __builtin_amdgcn_mfma_f32_16x16x32_bf16(a0, qf0, c, 0, 0, 0);
      c = __builtin_amdgcn_mfma_f32_16x16x32_bf16(a1, qf1, c, 0, 0, 0);
#pragma unroll
      for (int j = 0; j < 4; ++j) {
        float x = c[j];
        sv[kt][j] = x;
        tmax = fmaxf(tmax, x);
      }
    }
    __builtin_amdgcn_s_setprio(0);
    tmax = fmaxf(tmax, __shfl_xor(tmax, 16));
    tmax = fmaxf(tmax, __shfl_xor(tmax, 32));
    float m_new;
    if (__all(tmax <= m_run + 8.0f)) {
      m_new = m_run;
    } else {
      m_new = fmaxf(m_run, tmax);
      const float fac = __expf(m_run - m_new);
      float fj[4];
#pragma unroll
      for (int j = 0; j < 4; ++j) fj[j] = __shfl(fac, (lane & 48) | (g * 4 + j));
#pragma unroll
      for (int ct = 0; ct < 4; ++ct)
#pragma unroll
        for (int j = 0; j < 4; ++j) oacc[ct][j] *= fj[j];
      l_run *= fac;
    }
    float psum = 0.f;
#pragma unroll
    for (int kt = 0; kt < 4; ++kt) {
      short4v pk;
#pragma unroll
      for (int j = 0; j < 4; ++j) {
        float p = __expf(sv[kt][j] - m_new);
        psum += p;
        pk[j] = f2bf(p);
      }
      *(short4v*)(Pw + r * 72 + kt * 16 + g * 4) = pk;
    }
    psum += __shfl_xor(psum, 16);
    psum += __shfl_xor(psum, 32);
    l_run += psum;
    m_run = m_new;
    const short8v pa0 = *(const short8v*)(Pw + r * 72 + g * 8);
    const short8v pa1 = *(const short8v*)(Pw + r * 72 + 32 + g * 8);
    __builtin_amdgcn_s_setprio(1);
#pragma unroll
    for (int ct = 0; ct < 4; ++ct) {
      const int d = ct * 16 + r, sw = d & 7;
      short8v v0 = *(const short8v*)(Vc + d * 64 + ((g ^ sw) * 8));
      short8v v1 = *(const short8v*)(Vc + d * 64 + (((4 + g) ^ sw) * 8));
      oacc[ct] = __builtin_amdgcn_mfma_f32_16x16x32_bf16(pa0, v0, oacc[ct], 0, 0, 0);
      oacc[ct] = __builtin_amdgcn_mfma_f32_16x16x32_bf16(pa1, v1, oacc[ct], 0, 0, 0);
    }
    __builtin_amdgcn_s_setprio(0);
    asm volatile("s_waitcnt vmcnt(0)" ::: "memory");
    __builtin_amdgcn_s_barrier();
    cur ^= 1;
  }
  float li[4];
#pragma unroll
  for (int j = 0; j < 4; ++j)
    li[j] = 1.0f / __shfl(l_run, (lane & 48) | (g * 4 + j));
#pragma unroll
  for (int ct = 0; ct < 4; ++ct)
#pragma unroll
    for (int j = 0; j < 4; ++j)
      O[(size_t)(b * Ls + q0 + g * 4 + j) * DM + h * DHd + ct * 16 + r] =
          __float2bfloat16(oacc[ct][j] * li[j]);
}

// ---------------- ALL converts (2 activations + 10 weights) in one dispatch ----------------
struct CvtArgs { const float* s[12]; __hip_bfloat16* d[12]; };
__global__ __launch_bounds__(256) void k_cvt_all(CvtArgs a)
{
  const int bid = blockIdx.x, tid = threadIdx.x;
  if (bid < 8192) {
    const size_t half = (size_t)MR * DM / 4;
    size_t i = (size_t)bid * 256 + tid;
    const float* in = a.s[10]; __hip_bfloat16* out = a.d[10];
    if (i >= half) { i -= half; in = a.s[11]; out = a.d[11]; }
    float4 v = *reinterpret_cast<const float4*>(in + i * 4);
    short4v o;
    o.x = f2bf(v.x); o.y = f2bf(v.y); o.z = f2bf(v.z); o.w = f2bf(v.w);
    *reinterpret_cast<short4v*>(out + i * 4) = o;
    return;
  }
  __shared__ float t[32][33];
  const int wb = bid - 8192;
  int widx, K, N, kblk, nblk;
  if (wb < 2048) {
    widx = wb >> 8; const int w2 = wb & 255;
    K = 512; N = 512; kblk = w2 & 15; nblk = w2 >> 4;
  } else if (wb < 3072) {
    widx = 8; const int w2 = wb - 2048;
    K = 512; N = 2048; kblk = w2 & 15; nblk = w2 >> 4;
  } else {
    widx = 9; const int w2 = wb - 3072;
    K = 2048; N = 512; kblk = w2 & 63; nblk = w2 >> 6;
  }
  const float* W = a.s[widx];
  __hip_bfloat16* Wt = a.d[widx];
  const int k0 = kblk * 32, n0 = nblk * 32;
  const int r = tid >> 3, c = (tid & 7) * 4;
  float4 v = *reinterpret_cast<const float4*>(W + (size_t)(k0 + r) * N + n0 + c);
  t[r][c + 0] = v.x; t[r][c + 1] = v.y; t[r][c + 2] = v.z; t[r][c + 3] = v.w;
  __syncthreads();
  short4v o;
  o.x = f2bf(t[c + 0][r]); o.y = f2bf(t[c + 1][r]);
  o.z = f2bf(t[c + 2][r]); o.w = f2bf(t[c + 3][r]);
  *reinterpret_cast<short4v*>(Wt + (size_t)(n0 + r) * K + k0 + c) = o;
}

// ====== fused prob attention chunk (bf16 Q/K in, f32 compute) ======
__global__ __launch_bounds__(256) void k_probflash(
    const __hip_bfloat16* __restrict__ Qzb, const __hip_bfloat16* __restrict__ Kzb,
    const float* __restrict__ Vm, const int* __restrict__ top,
    float* __restrict__ Op, float* __restrict__ Ml, float* __restrict__ Ll,
    float* __restrict__ mvp, int U)
{
  __shared__ float Qs[DHd][64 + 4];
  __shared__ float Ks[DHd][64 + 4];
  __shared__ float Vs[64][64];
  __shared__ float ps[4][64];
  const int bid = blockIdx.x;
  const int swz = (bid & 7) * ((16 * ZH) >> 3) + (bid >> 3);
  const int kc = swz & 15, z = swz >> 4, b = z >> 3, h = z & 7;
  const int tid = threadIdx.x;
  const int k0 = kc * 64;
#pragma unroll
  for (int i = 0; i < 4; ++i) {
    const int idx = tid + (i << 8);
    const int r = idx >> 4, c4 = (idx & 15) << 2;
    int u = r; if (u >= U) u = U - 1;
    const int qr = top[z * U + u];
    short4v q4 = *reinterpret_cast<const short4v*>(Qzb + ((size_t)z * Ls + qr) * 64 + c4);
    Qs[c4 + 0][r] = bf2f(q4.x); Qs[c4 + 1][r] = bf2f(q4.y);
    Qs[c4 + 2][r] = bf2f(q4.z); Qs[c4 + 3][r] = bf2f(q4.w);
    short4v k4 = *reinterpret_cast<const short4v*>(Kzb + ((size_t)z * Ls + k0 + r) * 64 + c4);
    Ks[c4 + 0][r] = bf2f(k4.x); Ks[c4 + 1][r] = bf2f(k4.y);
    Ks[c4 + 2][r] = bf2f(k4.z); Ks[c4 + 3][r] = bf2f(k4.w);
    *reinterpret_cast<float4*>(&Vs[r][c4]) =
        *reinterpret_cast<const float4*>(Vm + ((size_t)(b * Ls + k0 + r)) * DM + h * DHd + c4);
  }
  __syncthreads();
  const int mB = (tid >> 4) << 2, nB = (tid & 15) << 2;
  float acc[4][4] = {};
#pragma unroll
  for (int kk = 0; kk < DHd; ++kk) {
    float4 a4 = *reinterpret_cast<const float4*>(&Qs[kk][mB]);
    float4 b4 = *reinterpret_cast<const float4*>(&Ks[kk][nB]);
    const float av[4] = {a4.x, a4.y, a4.z, a4.w};
#pragma unroll
    for (int i = 0; i < 4; ++i) {
      acc[i][0] += av[i] * b4.x; acc[i][1] += av[i] * b4.y;
      acc[i][2] += av[i] * b4.z; acc[i][3] += av[i] * b4.w;
    }
  }
  __syncthreads();
  float (*Ss)[68] = (float (*)[68])Qs;
#pragma unroll
  for (int i = 0; i < 4; ++i) {
    float4 o;
    o.x = acc[i][0] * 0.125f; o.y = acc[i][1] * 0.125f;
    o.z = acc[i][2] * 0.125f; o.w = acc[i][3] * 0.125f;
    *reinterpret_cast<float4*>(&Ss[mB + i][nB]) = o;
  }
  __syncthreads();
  {
    const int row = tid >> 2, q = tid & 3;
    float mx = -1e30f;
#pragma unroll
    for (int j = 0; j < 16; ++j) mx = fmaxf(mx, Ss[row][q * 16 + j]);
    mx = fmaxf(mx, __shfl_xor(mx, 1));
    mx = fmaxf(mx, __shfl_xor(mx, 2));
    float se = 0.f;
#pragma unroll
    for (int j = 0; j < 16; ++j) {
      float p = __expf(Ss[row][q * 16 + j] - mx);
      Ss[row][q * 16 + j] = p;
      se += p;
    }
    se += __shfl_xor(se, 1);
    se += __shfl_xor(se, 2);
    if (q == 0) {
      Ml[((size_t)kc * ZH + z) * 64 + row] = mx;
      Ll[((size_t)kc * ZH + z) * 64 + row] = se;
    }
  }
  __syncthreads();
  const int d = tid & 63, w = tid >> 6;
  {
    float s = 0.f;
#pragma unroll
    for (int i = 0; i < 16; ++i) s += Vs[w * 16 + i][d];
    ps[w][d] = s;
  }
  float acc2[16] = {};
  for (int k = 0; k < 64; ++k) {
    const float vk = Vs[k][d];
#pragma unroll
    for (int i = 0; i < 16; ++i)
      acc2[i] += Ss[w * 16 + i][k] * vk;
  }
  float* outb = Op + ((size_t)kc * ZH + z) * 4096;
#pragma unroll
  for (int i = 0; i < 16; ++i)
    outb[(w * 16 + i) * 64 + d] = acc2[i];
  __syncthreads();
  if (w == 0)
    mvp[((size_t)z * 16 + kc) * 64 + d] = ps[0][d] + ps[1][d] + ps[2][d] + ps[3][d];
}

// ------ per-z: meanV fill of whole slice + flash-combine scatter of top-U ------
__global__ __launch_bounds__(256) void k_prob_comb2(
    const float* __restrict__ Op, const float* __restrict__ Ml,
    const float* __restrict__ Ll, const int* __restrict__ top,
    const float* __restrict__ mvp, __hip_bfloat16* __restrict__ ctx, int U)
{
  __shared__ float wsh[16][64];
  __shared__ float Lsh[64];
  __shared__ short4v mvb[16];
  const int z = blockIdx.x, b = z >> 3, h = z & 7;
  const int tid = threadIdx.x;
  if (tid < 64) {
    float M = -1e30f;
#pragma unroll
    for (int c = 0; c < 16; ++c)
      M = fmaxf(M, Ml[((size_t)c * ZH + z) * 64 + tid]);
    float L = 0.f;
#pragma unroll
    for (int c = 0; c < 16; ++c) {
      float wv = __expf(Ml[((size_t)c * ZH + z) * 64 + tid] - M);
      wsh[c][tid] = wv;
      L += wv * Ll[((size_t)c * ZH + z) * 64 + tid];
    }
    Lsh[tid] = L;
    float s = 0.f;
#pragma unroll
    for (int c = 0; c < 16; ++c) s += mvp[((size_t)z * 16 + c) * 64 + tid];
    const short mb = f2bf(s * (1.0f / Ls));
    ((short*)mvb)[tid] = mb;
  }
  __syncthreads();
  __hip_bfloat16* base = ctx + (size_t)(b * Ls) * DM + h * DHd;
  for (int i = tid; i < 1024 * 16; i += 256) {
    const int row = i >> 4, c4 = i & 15;
    *reinterpret_cast<short4v*>(base + (size_t)row * DM + c4 * 4) = mvb[c4];
  }
  __syncthreads();
  for (int e = tid; e < U * 64; e += 256) {
    const int u = e >> 6, d = e & 63;
    float s = 0.f;
#pragma unroll
    for (int c = 0; c < 16; ++c)
      s += wsh[c][u] * Op[((size_t)c * ZH + z) * 4096 + u * 64 + d];
    const int row = top[z * U + u];
    ctx[((size_t)(b * Ls + row)) * DM + h * DHd + d] =
        __float2bfloat16(s / Lsh[u]);
  }
}

// ---- ProbSparse sampled scores, bf16 compact gather, 8 lanes/query ----
template<int UU>
__global__ __launch_bounds__(256) void k_mscore4(
    const __hip_bfloat16* __restrict__ Qzb, const __hip_bfloat16* __restrict__ Kzb,
    const int* __restrict__ smp, float* __restrict__ Ms)
{
  const int bid = blockIdx.x;
  const int swz = (bid & 7) * 256 + (bid >> 3);
  const int gw = swz * 4 + (threadIdx.x >> 6);
  const int lane = threadIdx.x & 63;
  const int li = lane >> 3, dp = (lane & 7) * 8;
  const int l = (gw & 127) * 8 + li;
  const int z = gw >> 7;
  const short8v q8 = *(const short8v*)(Qzb + ((size_t)z * Ls + l) * 64 + dp);
  float qf[8];
#pragma unroll
  for (int j = 0; j < 8; ++j) qf[j] = bf2f(q8[j]);
  int kidx[UU];
#pragma unroll
  for (int u = 0; u < UU; ++u) kidx[u] = smp[l * UU + u];
  const __hip_bfloat16* kzb = Kzb + (size_t)z * Ls * 64 + dp;
  float mx = -1e30f, sm = 0.f;
#pragma unroll
  for (int u = 0; u < UU; ++u) {
    const short8v k8 = *(const short8v*)(kzb + (size_t)kidx[u] * 64);
    float d = qf[0] * bf2f(k8[0]) + qf[1] * bf2f(k8[1])
            + qf[2] * bf2f(k8[2]) + qf[3] * bf2f(k8[3])
            + qf[4] * bf2f(k8[4]) + qf[5] * bf2f(k8[5])
            + qf[6] * bf2f(k8[6]) + qf[7] * bf2f(k8[7]);
    d += __shfl_xor(d, 1);
    d += __shfl_xor(d, 2);
    d += __shfl_xor(d, 4);
    mx = fmaxf(mx, d);
    sm += d;
  }
  if ((lane & 7) == 0) Ms[z * Ls + l] = mx - sm * (1.0f / Ls);
}

// runtime-U fallback
__global__ __launch_bounds__(256) void k_mscore4g(
    const __hip_bfloat16* __restrict__ Qzb, const __hip_bfloat16* __restrict__ Kzb,
    const int* __restrict__ smp, float* __restrict__ Ms, int U)
{
  const int bid = blockIdx.x;
  const int swz = (bid & 7) * 256 + (bid >> 3);
  const int gw = swz * 4 + (threadIdx.x >> 6);
  const int lane = threadIdx.x & 63;
  const int li = lane >> 3, dp = (lane & 7) * 8;
  const int l = (gw & 127) * 8 + li;
  const int z = gw >> 7;
  const short8v q8 = *(const short8v*)(Qzb + ((size_t)z * Ls + l) * 64 + dp);
  float qf[8];
#pragma unroll
  for (int j = 0; j < 8; ++j) qf[j] = bf2f(q8[j]);
  const __hip_bfloat16* kzb = Kzb + (size_t)z * Ls * 64 + dp;
  float mx = -1e30f, sm = 0.f;
  for (int u = 0; u < U; ++u) {
    const short8v k8 = *(const short8v*)(kzb + (size_t)smp[l * U + u] * 64);
    float d = qf[0] * bf2f(k8[0]) + qf[1] * bf2f(k8[1])
            + qf[2] * bf2f(k8[2]) + qf[3] * bf2f(k8[3])
            + qf[4] * bf2f(k8[4]) + qf[5] * bf2f(k8[5])
            + qf[6] * bf2f(k8[6]) + qf[7] * bf2f(k8[7]);
    d += __shfl_xor(d, 1);
    d += __shfl_xor(d, 2);
    d += __shfl_xor(d, 4);
    mx = fmaxf(mx, d);
    sm += d;
  }
  if ((lane & 7) == 0) Ms[z * Ls + l] = mx - sm * (1.0f / Ls);
}

// ---------------- wave-parallel top-U ----------------
__global__ __launch_bounds__(64) void k_topk_w(
    const float* __restrict__ Ms, int* __restrict__ top, int U)
{
  const int z = blockIdx.x, lane = threadIdx.x;
  float v[16];
#pragma unroll
  for (int j = 0; j < 16; ++j) v[j] = Ms[z * Ls + j * 64 + lane];
  for (int it = 0; it < U; ++it) {
    float bv = -1e30f; int bi = 0x7fffffff;
#pragma unroll
    for (int j = 0; j < 16; ++j) {
      const int idx = j * 64 + lane;
      if (v[j] > bv) { bv = v[j]; bi = idx; }
    }
#pragma unroll
    for (int off = 1; off < 64; off <<= 1) {
      const float ov = __shfl_xor(bv, off);
      const int   oi = __shfl_xor(bi, off);
      if (ov > bv || (ov == bv && oi < bi)) { bv = ov; bi = oi; }
    }
    if (lane == 0) top[z * U + it] = bi;
    if ((bi & 63) == lane) v[bi >> 6] = -1e30f;
  }
}

// ------- LayerNorm over sum of NP partials (+bias) (+residual) -------
template<int NP>
__global__ __launch_bounds__(256) void k_ln2(
    const float* __restrict__ x0, const float* __restrict__ x1,
    const float* __restrict__ x2, const float* __restrict__ x3,
    const float* __restrict__ res, const float* __restrict__ bias,
    const float* __restrict__ g, const float* __restrict__ be,
    float* __restrict__ outf, __hip_bfloat16* __restrict__ outb)
{
  __shared__ float red[4];
  const int row = blockIdx.x, tid = threadIdx.x;
  const size_t base = (size_t)row * DM;
  float2 v = *reinterpret_cast<const float2*>(x0 + base + tid * 2);
  if (NP > 1) {
    float2 a = *reinterpret_cast<const float2*>(x1 + base + tid * 2);
    v.x += a.x; v.y += a.y;
  }
  if (NP > 2) {
    float2 a = *reinterpret_cast<const float2*>(x2 + base + tid * 2);
    v.x += a.x; v.y += a.y;
  }
  if (NP > 3) {
    float2 a = *reinterpret_cast<const float2*>(x3 + base + tid * 2);
    v.x += a.x; v.y += a.y;
  }
  if (bias) {
    float2 a = *reinterpret_cast<const float2*>(bias + tid * 2);
    v.x += a.x; v.y += a.y;
  }
  if (res) {
    float2 r2 = *reinterpret_cast<const float2*>(res + base + tid * 2);
    v.x += r2.x; v.y += r2.y;
  }
  float s = v.x + v.y;
#pragma unroll
  for (int off = 32; off; off >>= 1) s += __shfl_xor(s, off);
  if ((tid & 63) == 0) red[tid >> 6] = s;
  __syncthreads();
  s = red[0] + red[1] + red[2] + red[3];
  const float mean = s * (1.0f / DM);
  __syncthreads();
  float dx = v.x - mean, dy = v.y - mean;
  float q = dx * dx + dy * dy;
#pragma unroll
  for (int off = 32; off; off >>= 1) q += __shfl_xor(q, off);
  if ((tid & 63) == 0) red[tid >> 6] = q;
  __syncthreads();
  q = red[0] + red[1] + red[2] + red[3];
  const float inv = rsqrtf(q * (1.0f / DM) + 1e-5f);
  float2 gg = *reinterpret_cast<const float2*>(g + tid * 2);
  float2 bb = *reinterpret_cast<const float2*>(be + tid * 2);
  float ox = dx * inv * gg.x + bb.x;
  float oy = dy * inv * gg.y + bb.y;
  if (outf) {
    float2 o; o.x = ox; o.y = oy;
    *reinterpret_cast<float2*>(outf + base + tid * 2) = o;
  }
  if (outb) {
    short2 ob; ob.x = f2bf(ox); ob.y = f2bf(oy);
    *reinterpret_cast<short2*>(outb + base + tid * 2) = ob;
  }
}

extern "C" void kernel_launch(void* const* d_in, const int* in_sizes, int n_in,
                              void* d_out, int out_size, void* d_ws, size_t ws_size,
                              hipStream_t stream)
{
  const float* tgt = (const float*)d_in[0];
  const float* mem = (const float*)d_in[1];
  const int*   smp = (const int*)d_in[2];
  const float* wq1 = (const float*)d_in[3];  const float* bq1 = (const float*)d_in[4];
  const float* wk1 = (const float*)d_in[5];  const float* bk1 = (const float*)d_in[6];
  const float* wv1 = (const float*)d_in[7];  const float* bv1 = (const float*)d_in[8];
  const float* wo1 = (const float*)d_in[9];  const float* bo1 = (const float*)d_in[10];
  const float* wq2 = (const float*)d_in[11]; const float* bq2 = (const float*)d_in[12];
  const float* wk2 = (const float*)d_in[13]; const float* bk2 = (const float*)d_in[14];
  const float* wv2 = (const float*)d_in[15]; const float* bv2 = (const float*)d_in[16];
  const float* wo2 = (const float*)d_in[17]; const float* bo2 = (const float*)d_in[18];
  const float* c1w = (const float*)d_in[19]; const float* c1b = (const float*)d_in[20];
  const float* c2w = (const float*)d_in[21]; const float* c2b = (const float*)d_in[22];
  const float* g1  = (const float*)d_in[23]; const float* be1 = (const float*)d_in[24];
  const float* g2  = (const float*)d_in[25]; const float* be2 = (const float*)d_in[26];
  const float* g3  = (const float*)d_in[27]; const float* be3 = (const float*)d_in[28];
  float* outp = (float*)d_out;

  const int U   = in_sizes[2] / Ls;            // 35

  char* ws = (char*)d_ws;
  const size_t SZ = (size_t)MR * DM * sizeof(float);       // 16.78 MB
  float* W0   = (float*)(ws);
  float* W1   = (float*)(ws + SZ);
  float* W2   = (float*)(ws + 2 * SZ);
  float* Sbuf = (float*)(ws + 3 * SZ);                     // FFN hidden / QKzb region
  float* Op   = Sbuf + (size_t)ZH * 64 * Ls;               // prob PV partials
  __hip_bfloat16* QKzb = (__hip_bfloat16*)Sbuf;            // Qzb, then Kzb
  __hip_bfloat16* Qzb = QKzb;
  __hip_bfloat16* Kzb = QKzb + (size_t)ZH * Ls * 64;
  __hip_bfloat16* Tb  = (__hip_bfloat16*)(ws + 5 * SZ);
  __hip_bfloat16* Mb  = (__hip_bfloat16*)(ws + 5 * SZ + SZ / 2);
  __hip_bfloat16* Xb  = (__hip_bfloat16*)(ws + 6 * SZ);
  __hip_bfloat16* Vtb = (__hip_bfloat16*)(ws + 6 * SZ + SZ / 2);
  __hip_bfloat16* Wt3 = Vtb;                 // [wq1b;wk1b;wv1b] (dead before Vtb written)
  char* tail = ws + 7 * SZ;
  __hip_bfloat16* wo1b = (__hip_bfloat16*)tail; tail += DM * DM * 2;
  __hip_bfloat16* wq2b = (__hip_bfloat16*)tail; tail += DM * DM * 2;
  __hip_bfloat16* wk2b = (__hip_bfloat16*)tail; tail += DM * DM * 2;
  __hip_bfloat16* wv2b = (__hip_bfloat16*)tail; tail += DM * DM * 2;
  __hip_bfloat16* wo2b = (__hip_bfloat16*)tail; tail += DM * DM * 2;
  __hip_bfloat16* c1wb = (__hip_bfloat16*)tail; tail += DM * 4 * DM * 2;
  __hip_bfloat16* c2wb = (__hip_bfloat16*)tail; tail += DM * 4 * DM * 2;
  float* Ms  = (float*)tail; tail += (size_t)ZH * Ls * 4;
  int*   top = (int*)tail;   tail += (size_t)ZH * 64 * 4;
  float* mvp = (float*)tail; tail += (size_t)ZH * 16 * DHd * 4;
  float* Ml  = (float*)tail; tail += (size_t)16 * ZH * 64 * 4;
  float* Ll  = (float*)tail; tail += (size_t)16 * ZH * 64 * 4;
  __hip_bfloat16* Kb = Tb;
  __hip_bfloat16* Qb = (__hip_bfloat16*)d_out;  // parked until final LN
  __hip_bfloat16* hb = (__hip_bfloat16*)Sbuf;

  // ---- ALL converts, one dispatch ----
  CvtArgs ca;
  ca.s[0] = wq1; ca.d[0] = Wt3;
  ca.s[1] = wk1; ca.d[1] = Wt3 + DM * DM;
  ca.s[2] = wv1; ca.d[2] = Wt3 + 2 * DM * DM;
  ca.s[3] = wo1; ca.d[3] = wo1b;
  ca.s[4] = wq2; ca.d[4] = wq2b;
  ca.s[5] = wk2; ca.d[5] = wk2b;
  ca.s[6] = wv2; ca.d[6] = wv2b;
  ca.s[7] = wo2; ca.d[7] = wo2b;
  ca.s[8] = c1w; ca.d[8] = c1wb;
  ca.s[9] = c2w; ca.d[9] = c2wb;
  ca.s[10] = tgt; ca.d[10] = Tb;
  ca.s[11] = mem; ca.d[11] = Mb;
  k_cvt_all<<<dim3(12288), 256, 0, stream>>>(ca);

  // ---- layer-1 projections: ONE batched GEMM (Q->Qzb, K->Kzb, V->W2 f32) ----
  k_gemm_mfma<10, 0, 128><<<dim3(MR / 128, 12), 256, 0, stream>>>(
      Tb, Wt3, bq1, bk1, bv1, nullptr, nullptr, W2, QKzb, MR, 1536, DM);

  // ---- ProbSparse ----
  if (U == 35)
    k_mscore4<35><<<dim3(2048), 256, 0, stream>>>(Qzb, Kzb, smp, Ms);
  else
    k_mscore4g<<<dim3(2048), 256, 0, stream>>>(Qzb, Kzb, smp, Ms, U);
  k_topk_w<<<dim3(ZH), 64, 0, stream>>>(Ms, top, U);
  k_probflash<<<dim3(16 * ZH), 256, 0, stream>>>(Qzb, Kzb, W2, top, Op, Ml, Ll, mvp, U);
  k_prob_comb2<<<dim3(ZH), 256, 0, stream>>>(Op, Ml, Ll, top, mvp, Xb, U);

  // ---- out-proj 1 (64-row tile, no split-K) + residual LN ----
  k_gemm_mfma<20, 0, 64><<<dim3(MR / 64, DM / 128, 1), 256, 0, stream>>>(
      Xb, wo1b, nullptr, nullptr, nullptr, W0, nullptr, nullptr, nullptr, MR, DM, DM);
  k_ln2<1><<<dim3(MR), 256, 0, stream>>>(W0, nullptr, nullptr, nullptr,
                                         tgt, bo1, g1, be1, nullptr, Xb);

  // ---- layer-2 projections: ONE triple (Q from Xb; K,V from Mb via aux3) ----
  k_gemm_mfma<12, 0, 128><<<dim3(MR / 128, 12), 256, 0, stream>>>(
      Xb, wq2b, bq2, bk2, bv2, Qb, Kb, Vtb, (void*)Mb, MR, 1536, DM);

  // ---- fused flash cross attention -> Xb (bf16) ----
  k_flash2<<<dim3(Ls / 128, ZH), 512, 0, stream>>>(Qb, Kb, Vtb, Xb);

  // ---- out-proj 2 (64-row tile) + LN ----
  k_gemm_mfma<20, 0, 64><<<dim3(MR / 64, DM / 128, 1), 256, 0, stream>>>(
      Xb, wo2b, nullptr, nullptr, nullptr, W0, nullptr, nullptr, nullptr, MR, DM, DM);
  k_ln2<1><<<dim3(MR), 256, 0, stream>>>(W0, nullptr, nullptr, nullptr,
                                         nullptr, bo2, g2, be2, W1, Xb);

  // ---- FFN ----
  k_gemm_mfma<1, 1, 128><<<dim3(MR / 128, 4 * DM / 128), 256, 0, stream>>>(
      Xb, c1wb, c1b, nullptr, nullptr, hb, nullptr, nullptr, nullptr, MR, 4 * DM, DM);
  k_gemm_mfma<20, 0, 64><<<dim3(MR / 64, DM / 128, 1), 256, 0, stream>>>(
      hb, c2wb, nullptr, nullptr, nullptr, W0, nullptr, nullptr, nullptr, MR, DM, 4 * DM);
  k_ln2<1><<<dim3(MR), 256, 0, stream>>>(W0, nullptr, nullptr, nullptr,
                                         W1, c2b, g3, be3, outp, nullptr);
}